// Round 1
// baseline (2779.011 us; speedup 1.0000x reference)
//
#include <hip/hip_runtime.h>
#include <hip/hip_bf16.h>
#include <math.h>

// ---------------------------------------------------------------------------
// MoE: 8 shared SwiGLU experts (averaged) + 32 routed GELU experts (top-4)
// T=4096 tokens, D=768, F_shared=2304, F_routed=1536, rank-64 router.
// Strategy round 1: fp32 router (selection-exact), bf16 MFMA GEMMs with
// fused activations, K-concat over experts for the down-projections.
// ---------------------------------------------------------------------------

#define T_TOK 4096
#define DHID 768
#define NE_R 32
#define NE_S 8
#define F_S 2304
#define F_R 1536

typedef float f32x4 __attribute__((ext_vector_type(4)));
typedef short s16x8 __attribute__((ext_vector_type(8)));

__device__ __forceinline__ short f2bf(float f) {
  union { float f; unsigned u; } v; v.f = f;
  unsigned r = v.u + 0x7fffu + ((v.u >> 16) & 1u);   // RNE
  return (short)(r >> 16);
}

// async global->LDS, 16B per lane, wave-uniform LDS base
#define GLD16(gsrc, ldst)                                                     \
  __builtin_amdgcn_global_load_lds(                                           \
      (const __attribute__((address_space(1))) void*)(gsrc),                  \
      (__attribute__((address_space(3))) void*)(ldst), 16, 0, 0)

// ---------------------------------------------------------------------------
// x fp32 -> bf16 (vectorized)
__global__ __launch_bounds__(256) void cvt_x_kernel(const float* __restrict__ in,
                                                    short* __restrict__ out, int n4) {
  int i = blockIdx.x * 256 + threadIdx.x;
  if (i >= n4) return;
  float4 v = ((const float4*)in)[i];
  short4 o;
  o.x = f2bf(v.x); o.y = f2bf(v.y); o.z = f2bf(v.z); o.w = f2bf(v.w);
  ((short4*)out)[i] = o;
}

// ---------------------------------------------------------------------------
// Batched transpose+convert: out[c*ldo + r] (bf16) = in[r*C + c] (f32)
// batch b: in += b*R*C, out += b*out_bstride. All dims multiples of 32.
__global__ __launch_bounds__(256) void transpose_cvt(const float* __restrict__ in,
                                                     short* __restrict__ out,
                                                     int R, int C, long ldo, long out_bstride) {
  __shared__ float tile[32][33];
  int b = blockIdx.z;
  in += (size_t)b * R * C;
  out += (size_t)b * out_bstride;
  int c0 = blockIdx.x * 32, r0 = blockIdx.y * 32;
  int tx = threadIdx.x, ty = threadIdx.y;  // 32 x 8
#pragma unroll
  for (int i = 0; i < 32; i += 8)
    tile[ty + i][tx] = in[(size_t)(r0 + ty + i) * C + (c0 + tx)];
  __syncthreads();
#pragma unroll
  for (int i = 0; i < 32; i += 8)
    out[(size_t)(c0 + ty + i) * ldo + (r0 + tx)] = f2bf(tile[tx][ty + i]);
}

// ---------------------------------------------------------------------------
// Router: fp32, one wave per token. Writes dense gate array wfull[t][32]
// (0 for unselected), counts (int atomics), per-token entropy partials.
__global__ __launch_bounds__(64) void router_kernel(const float* __restrict__ x,
    const float* __restrict__ rdown, const float* __restrict__ rup,
    float* __restrict__ wfull, int* __restrict__ counts, float* __restrict__ pent) {
  int t = blockIdx.x;
  int lane = threadIdx.x;
  __shared__ float xs[DHID];
  __shared__ float xrs[64];
  __shared__ float lg[32];
  __shared__ float wsel[32];
  const float* xt = x + (size_t)t * DHID;
  for (int i = lane; i < DHID; i += 64) xs[i] = xt[i];
  __syncthreads();
  float acc = 0.f;
#pragma unroll 8
  for (int d = 0; d < DHID; ++d) acc += xs[d] * rdown[d * 64 + lane];
  xrs[lane] = acc;
  __syncthreads();
  if (lane < 32) {
    float l = 0.f;
#pragma unroll 8
    for (int r = 0; r < 64; ++r) l += xrs[r] * rup[r * 32 + lane];
    lg[lane] = l;
  }
  __syncthreads();
  if (lane == 0) {
    int sel[4]; float sv[4];
    unsigned taken = 0;
    for (int k = 0; k < 4; ++k) {            // top-4, ties -> lowest index
      float best = -3.4e38f; int bi = 0;
      for (int e = 0; e < 32; ++e)
        if (!((taken >> e) & 1u) && lg[e] > best) { best = lg[e]; bi = e; }
      taken |= 1u << bi; sel[k] = bi; sv[k] = best;
    }
    float m = sv[0];
    float wv[4]; float zs = 0.f;
    for (int k = 0; k < 4; ++k) { wv[k] = __expf(sv[k] - m); zs += wv[k]; }
    for (int e = 0; e < 32; ++e) wsel[e] = 0.f;
    for (int k = 0; k < 4; ++k) {
      wsel[sel[k]] = wv[k] / zs;
      atomicAdd(&counts[sel[k]], 1);
    }
    float Z = 0.f;
    for (int e = 0; e < 32; ++e) Z += __expf(lg[e] - m);
    float ent = 0.f;
    for (int e = 0; e < 32; ++e) {
      float p = __expf(lg[e] - m) / Z;
      ent -= p * logf(p + 1e-10f);
    }
    pent[t] = ent;
  }
  __syncthreads();
  if (lane < 32) wfull[(size_t)t * 32 + lane] = wsel[lane];
}

// ---------------------------------------------------------------------------
// bf16 MFMA GEMM, A [M,K] row-major, B^T [N,K] row-major, BK=32, 4 waves.
// MODE 0: dual-B (gate,up), epilogue silu(g)*u -> bf16 H
// MODE 1: single-B, epilogue gelu_exact(v)*wrow[row] -> bf16 H
// MODE 2: single-B, epilogue fp32 out (+= if beta)
template<int BM, int BN, int MODE>
__global__ __launch_bounds__(256) void gemm_bt(
    const short* __restrict__ A, const short* __restrict__ B, const short* __restrict__ B2,
    short* __restrict__ outH, float* __restrict__ outF, const float* __restrict__ wrow,
    int K, long ldo, long bz, long coloffz, int e0, int beta) {
  constexpr int WM = BM / 2, WN = BN / 2;
  constexpr int FM = WM / 16, FN = WN / 16;
  __shared__ short As[BM * 32];
  __shared__ short Bs[BN * 32];
  __shared__ short Bs2[(MODE == 0) ? BN * 32 : 64];

  int tid = threadIdx.x;
  int wv = tid >> 6, lane = tid & 63;
  int wr = wv >> 1, wc = wv & 1;
  int lrow = lane & 15, kg = lane >> 4;
  int z = blockIdx.z;
  int m0 = blockIdx.y * BM, n0 = blockIdx.x * BN;

  const short* Ab = A + (size_t)m0 * K;
  const short* Bb = B + (size_t)z * bz + (size_t)n0 * K;
  const short* B2b = B2 ? (B2 + (size_t)z * bz + (size_t)n0 * K) : B;

  f32x4 acc[FM][FN] = {};
  f32x4 acc2[(MODE == 0) ? FM : 1][(MODE == 0) ? FN : 1] = {};

  for (int kt = 0; kt < K; kt += 32) {
#pragma unroll
    for (int it = 0; it < BM / 64; ++it) {
      int ci = tid + it * 256;
      GLD16(Ab + (size_t)(ci >> 2) * K + kt + (ci & 3) * 8, As + (wv * 64 + it * 256) * 8);
    }
#pragma unroll
    for (int it = 0; it < BN / 64; ++it) {
      int ci = tid + it * 256;
      GLD16(Bb + (size_t)(ci >> 2) * K + kt + (ci & 3) * 8, Bs + (wv * 64 + it * 256) * 8);
      if constexpr (MODE == 0)
        GLD16(B2b + (size_t)(ci >> 2) * K + kt + (ci & 3) * 8, Bs2 + (wv * 64 + it * 256) * 8);
    }
    __syncthreads();
    s16x8 af[FM], bfr[FN], bfr2[(MODE == 0) ? FN : 1];
#pragma unroll
    for (int i = 0; i < FM; ++i)
      af[i] = *(const s16x8*)&As[(wr * WM + i * 16 + lrow) * 32 + kg * 8];
#pragma unroll
    for (int j = 0; j < FN; ++j) {
      bfr[j] = *(const s16x8*)&Bs[(wc * WN + j * 16 + lrow) * 32 + kg * 8];
      if constexpr (MODE == 0)
        bfr2[j] = *(const s16x8*)&Bs2[(wc * WN + j * 16 + lrow) * 32 + kg * 8];
    }
#pragma unroll
    for (int i = 0; i < FM; ++i)
#pragma unroll
      for (int j = 0; j < FN; ++j) {
        acc[i][j] = __builtin_amdgcn_mfma_f32_16x16x32_bf16(af[i], bfr[j], acc[i][j], 0, 0, 0);
        if constexpr (MODE == 0)
          acc2[i][j] = __builtin_amdgcn_mfma_f32_16x16x32_bf16(af[i], bfr2[j], acc2[i][j], 0, 0, 0);
      }
    __syncthreads();
  }
  // epilogue: C/D layout col=lane&15, row=(lane>>4)*4+r  [verified m89]
#pragma unroll
  for (int i = 0; i < FM; ++i) {
#pragma unroll
    for (int r = 0; r < 4; ++r) {
      int row = m0 + wr * WM + i * 16 + kg * 4 + r;
      float wsc = 0.f;
      if constexpr (MODE == 1) wsc = wrow[(size_t)row * 32 + e0 + z];
#pragma unroll
      for (int j = 0; j < FN; ++j) {
        int col = n0 + wc * WN + j * 16 + lrow;
        float v = acc[i][j][r];
        if constexpr (MODE == 0) {
          float u = acc2[i][j][r];
          float h = v / (1.f + __expf(-v)) * u;            // silu(g)*u
          outH[(size_t)row * ldo + (size_t)z * coloffz + col] = f2bf(h);
        } else if constexpr (MODE == 1) {
          float h = 0.5f * v * (1.f + erff(v * 0.70710678118f)) * wsc;  // exact gelu * gate
          outH[(size_t)row * ldo + (size_t)z * coloffz + col] = f2bf(h);
        } else {
          size_t idx = (size_t)row * ldo + col;
          outF[idx] = (beta ? outF[idx] : 0.f) + v;
        }
      }
    }
  }
}

// ---------------------------------------------------------------------------
// combine: out = sacc/8 + racc; per-token norms -> partials
__global__ __launch_bounds__(256) void combine_kernel(const float* __restrict__ sacc,
    const float* __restrict__ racc, float* __restrict__ out, float* __restrict__ pnorm) {
  int t = blockIdx.x, tid = threadIdx.x;
  size_t base = (size_t)t * DHID;
  float s2 = 0.f, r2 = 0.f;
  for (int d = tid; d < DHID; d += 256) {
    float s = sacc[base + d] * 0.125f;
    float r = racc[base + d];
    out[base + d] = s + r;
    s2 += s * s; r2 += r * r;
  }
  for (int o = 32; o > 0; o >>= 1) { s2 += __shfl_down(s2, o); r2 += __shfl_down(r2, o); }
  __shared__ float red[8];
  int wv = tid >> 6, lane = tid & 63;
  if (lane == 0) { red[wv] = s2; red[4 + wv] = r2; }
  __syncthreads();
  if (tid == 0) {
    float st = red[0] + red[1] + red[2] + red[3];
    float rt = red[4] + red[5] + red[6] + red[7];
    pnorm[t] = sqrtf(st);
    pnorm[T_TOK + t] = sqrtf(rt);
  }
}

__global__ __launch_bounds__(256) void finalize_kernel(const int* __restrict__ counts,
    const float* __restrict__ pent, const float* __restrict__ pnorm, float* __restrict__ o) {
  int tid = threadIdx.x;
  float es = 0.f, ss = 0.f, rs = 0.f;
  for (int i = tid; i < T_TOK; i += 256) {
    es += pent[i]; ss += pnorm[i]; rs += pnorm[T_TOK + i];
  }
  float vs = 0.f;
  if (tid < 32) { float d = (float)counts[tid] - 512.f; vs = d * d; }
  for (int off = 32; off > 0; off >>= 1) {
    es += __shfl_down(es, off); ss += __shfl_down(ss, off);
    rs += __shfl_down(rs, off); vs += __shfl_down(vs, off);
  }
  __shared__ float red[16];
  int wv = tid >> 6, lane = tid & 63;
  if (lane == 0) { red[wv] = es; red[4 + wv] = ss; red[8 + wv] = rs; red[12 + wv] = vs; }
  __syncthreads();
  if (tid == 0) {
    es = red[0] + red[1] + red[2] + red[3];
    ss = red[4] + red[5] + red[6] + red[7];
    rs = red[8] + red[9] + red[10] + red[11];
    vs = red[12] + red[13] + red[14] + red[15];
    o[0] = vs / 31.f;                    // load_balance_loss (ddof=1, mean=512 exact)
    o[1] = es / (float)T_TOK;            // router_entropy
    o[2] = fabsf(ss - rs) / (float)T_TOK;// balance_loss
  }
}

__global__ void zero_kernel(int* counts) {
  if (threadIdx.x < 32) counts[threadIdx.x] = 0;
}

// ---------------------------------------------------------------------------
extern "C" void kernel_launch(void* const* d_in, const int* in_sizes, int n_in,
                              void* d_out, int out_size, void* d_ws, size_t ws_size,
                              hipStream_t stream) {
  const float* x   = (const float*)d_in[0];
  const float* swg = (const float*)d_in[1];
  const float* swu = (const float*)d_in[2];
  const float* swd = (const float*)d_in[3];
  const float* rw1 = (const float*)d_in[4];
  const float* rw2 = (const float*)d_in[5];
  const float* rdn = (const float*)d_in[6];
  const float* rup = (const float*)d_in[7];
  float* fout = (float*)d_out;

  // ---- workspace layout ----
  char* w = (char*)d_ws;
  size_t off = 0;
  auto take = [&](size_t bytes) { char* p = w + off; off = (off + bytes + 255) & ~(size_t)255; return p; };
  short* xbf   = (short*)take((size_t)T_TOK * DHID * 2);
  float* wfull = (float*)take((size_t)T_TOK * 32 * 4);
  int*   counts= (int*)  take(32 * 4);
  float* pent  = (float*)take((size_t)T_TOK * 4);
  float* pnorm = (float*)take((size_t)2 * T_TOK * 4);
  float* sacc  = (float*)take((size_t)T_TOK * DHID * 4);
  float* racc  = (float*)take((size_t)T_TOK * DHID * 4);
  size_t persist = off;
  size_t avail = (ws_size > persist) ? (ws_size - persist) : 0;

  const size_t SH_PER_E = (size_t)3 * F_S * DHID * 2 + (size_t)T_TOK * F_S * 2; // 29,491,200
  const size_t RT_PER_E = (size_t)2 * F_R * DHID * 2 + (size_t)T_TOK * F_R * 2; // 17,301,504
  int ES = (avail >= 8 * SH_PER_E) ? 8 : (avail >= 4 * SH_PER_E) ? 4 : (avail >= 2 * SH_PER_E) ? 2 : 1;
  int ER = (avail >= 32 * RT_PER_E) ? 32 : (avail >= 16 * RT_PER_E) ? 16 :
           (avail >= 8 * RT_PER_E) ? 8 : (avail >= 4 * RT_PER_E) ? 4 :
           (avail >= 2 * RT_PER_E) ? 2 : 1;
  char* arena = w + persist;

  // ---- small/setup kernels ----
  zero_kernel<<<1, 64, 0, stream>>>(counts);
  cvt_x_kernel<<<(T_TOK * DHID / 4 + 255) / 256, 256, 0, stream>>>(x, xbf, T_TOK * DHID / 4);
  router_kernel<<<T_TOK, 64, 0, stream>>>(x, rdn, rup, wfull, counts, pent);

  // ---- shared experts ----
  {
    short* wgT = (short*)arena;
    short* wuT = wgT + (size_t)ES * F_S * DHID;
    short* wdT = wuT + (size_t)ES * F_S * DHID;
    short* Hsh = wdT + (size_t)ES * F_S * DHID;
    for (int e0 = 0; e0 < NE_S; e0 += ES) {
      transpose_cvt<<<dim3(F_S / 32, DHID / 32, ES), dim3(32, 8), 0, stream>>>(
          swg + (size_t)e0 * DHID * F_S, wgT, DHID, F_S, DHID, (long)F_S * DHID);
      transpose_cvt<<<dim3(F_S / 32, DHID / 32, ES), dim3(32, 8), 0, stream>>>(
          swu + (size_t)e0 * DHID * F_S, wuT, DHID, F_S, DHID, (long)F_S * DHID);
      transpose_cvt<<<dim3(DHID / 32, F_S / 32, ES), dim3(32, 8), 0, stream>>>(
          swd + (size_t)e0 * F_S * DHID, wdT, F_S, DHID, (long)ES * F_S, (long)F_S);
      gemm_bt<128, 128, 0><<<dim3(F_S / 128, T_TOK / 128, ES), 256, 0, stream>>>(
          xbf, wgT, wuT, Hsh, nullptr, nullptr, DHID, (long)ES * F_S, (long)F_S * DHID, (long)F_S, 0, 0);
      gemm_bt<128, 64, 2><<<dim3(DHID / 64, T_TOK / 128, 1), 256, 0, stream>>>(
          Hsh, wdT, nullptr, nullptr, sacc, nullptr, ES * F_S, DHID, 0, 0, 0, e0 > 0);
    }
  }

  // ---- routed experts (dense over experts; gate weight fused in GEMM1 epilogue) ----
  {
    short* w1T = (short*)arena;
    short* w2T = w1T + (size_t)ER * F_R * DHID;
    short* Hr  = w2T + (size_t)ER * F_R * DHID;
    for (int e0 = 0; e0 < NE_R; e0 += ER) {
      transpose_cvt<<<dim3(F_R / 32, DHID / 32, ER), dim3(32, 8), 0, stream>>>(
          rw1 + (size_t)e0 * DHID * F_R, w1T, DHID, F_R, DHID, (long)F_R * DHID);
      transpose_cvt<<<dim3(DHID / 32, F_R / 32, ER), dim3(32, 8), 0, stream>>>(
          rw2 + (size_t)e0 * F_R * DHID, w2T, F_R, DHID, (long)ER * F_R, (long)F_R);
      gemm_bt<128, 128, 1><<<dim3(F_R / 128, T_TOK / 128, ER), 256, 0, stream>>>(
          xbf, w1T, nullptr, Hr, nullptr, wfull, DHID, (long)ER * F_R, (long)F_R * DHID, (long)F_R, e0, 0);
      gemm_bt<128, 64, 2><<<dim3(DHID / 64, T_TOK / 128, 1), 256, 0, stream>>>(
          Hr, w2T, nullptr, nullptr, racc, nullptr, ER * F_R, DHID, 0, 0, 0, e0 > 0);
    }
  }

  // ---- combine + scalars ----
  combine_kernel<<<T_TOK, 256, 0, stream>>>(sacc, racc, fout, pnorm);
  finalize_kernel<<<1, 256, 0, stream>>>(counts, pent, pnorm, fout + (size_t)T_TOK * DHID);
}

// Round 2
// 1330.005 us; speedup vs baseline: 2.0895x; 2.0895x over previous
//
#include <hip/hip_runtime.h>
#include <hip/hip_bf16.h>
#include <math.h>

// ---------------------------------------------------------------------------
// MoE round 2: sparse routed experts (top-4 gather/compaction), shared SwiGLU
// with per-expert split-K partials. fp32 router (selection-exact).
// ---------------------------------------------------------------------------

#define T_TOK 4096
#define DHID 768
#define NE_R 32
#define NE_S 8
#define F_S 2304
#define F_R 1536
#define MAXROWS 20480   // 160 tiles * 128
#define MAX_TILES 160

typedef float f32x4 __attribute__((ext_vector_type(4)));
typedef short s16x8 __attribute__((ext_vector_type(8)));

__device__ __forceinline__ short f2bf(float f) {
  union { float f; unsigned u; } v; v.f = f;
  unsigned r = v.u + 0x7fffu + ((v.u >> 16) & 1u);   // RNE
  return (short)(r >> 16);
}

// async global->LDS, 16B per lane, wave-uniform LDS base (per-lane global src OK)
#define GLD16(gsrc, ldst)                                                     \
  __builtin_amdgcn_global_load_lds(                                           \
      (const __attribute__((address_space(1))) void*)(gsrc),                  \
      (__attribute__((address_space(3))) void*)(ldst), 16, 0, 0)

// ---------------------------------------------------------------------------
__global__ __launch_bounds__(256) void cvt_x_kernel(const float* __restrict__ in,
                                                    short* __restrict__ out, int n4) {
  int i = blockIdx.x * 256 + threadIdx.x;
  if (i >= n4) return;
  float4 v = ((const float4*)in)[i];
  short4 o;
  o.x = f2bf(v.x); o.y = f2bf(v.y); o.z = f2bf(v.z); o.w = f2bf(v.w);
  ((short4*)out)[i] = o;
}

// ---------------------------------------------------------------------------
// Batched transpose+convert: out[c*ldo + r] (bf16) = in[r*C + c] (f32)
__global__ __launch_bounds__(256) void transpose_cvt(const float* __restrict__ in,
                                                     short* __restrict__ out,
                                                     int R, int C, long ldo, long out_bstride) {
  __shared__ float tile[32][33];
  int b = blockIdx.z;
  in += (size_t)b * R * C;
  out += (size_t)b * out_bstride;
  int c0 = blockIdx.x * 32, r0 = blockIdx.y * 32;
  int tx = threadIdx.x, ty = threadIdx.y;  // 32 x 8
#pragma unroll
  for (int i = 0; i < 32; i += 8)
    tile[ty + i][tx] = in[(size_t)(r0 + ty + i) * C + (c0 + tx)];
  __syncthreads();
#pragma unroll
  for (int i = 0; i < 32; i += 8)
    out[(size_t)(c0 + ty + i) * ldo + (r0 + tx)] = f2bf(tile[tx][ty + i]);
}

// ---------------------------------------------------------------------------
// Router: fp32, one wave per token. sel[t][4], w4[t][4], counts, entropy.
__global__ __launch_bounds__(64) void router_kernel(const float* __restrict__ x,
    const float* __restrict__ rdown, const float* __restrict__ rup,
    int* __restrict__ sel, float* __restrict__ w4, int* __restrict__ counts,
    float* __restrict__ pent) {
  int t = blockIdx.x;
  int lane = threadIdx.x;
  __shared__ float xs[DHID];
  __shared__ float xrs[64];
  __shared__ float lg[32];
  const float* xt = x + (size_t)t * DHID;
  for (int i = lane; i < DHID; i += 64) xs[i] = xt[i];
  __syncthreads();
  float acc = 0.f;
#pragma unroll 8
  for (int d = 0; d < DHID; ++d) acc += xs[d] * rdown[d * 64 + lane];
  xrs[lane] = acc;
  __syncthreads();
  if (lane < 32) {
    float l = 0.f;
#pragma unroll 8
    for (int r = 0; r < 64; ++r) l += xrs[r] * rup[r * 32 + lane];
    lg[lane] = l;
  }
  __syncthreads();
  if (lane == 0) {
    int si[4]; float sv[4];
    unsigned taken = 0;
    for (int k = 0; k < 4; ++k) {            // top-4, ties -> lowest index
      float best = -3.4e38f; int bi = 0;
      for (int e = 0; e < 32; ++e)
        if (!((taken >> e) & 1u) && lg[e] > best) { best = lg[e]; bi = e; }
      taken |= 1u << bi; si[k] = bi; sv[k] = best;
    }
    float m = sv[0];
    float wv[4]; float zs = 0.f;
    for (int k = 0; k < 4; ++k) { wv[k] = __expf(sv[k] - m); zs += wv[k]; }
    for (int k = 0; k < 4; ++k) {
      sel[t * 4 + k] = si[k];
      w4[t * 4 + k] = wv[k] / zs;
      atomicAdd(&counts[si[k]], 1);
    }
    float Z = 0.f;
    for (int e = 0; e < 32; ++e) Z += __expf(lg[e] - m);
    float ent = 0.f;
    for (int e = 0; e < 32; ++e) {
      float p = __expf(lg[e] - m) / Z;
      ent -= p * logf(p + 1e-10f);
    }
    pent[t] = ent;
  }
}

// ---------------------------------------------------------------------------
__global__ void zero_kernel(int* __restrict__ tlist, float* __restrict__ wslot,
                            int* __restrict__ counts, int* __restrict__ cursor) {
  int i = blockIdx.x * 256 + threadIdx.x;
  if (i < MAXROWS) { tlist[i] = 0; wslot[i] = 0.f; }
  if (i < 32) { counts[i] = 0; cursor[i] = 0; }
}

// meta[e] = tile_base prefix (tiles of 128), meta[32] = total tiles
__global__ void meta_kernel(const int* __restrict__ counts, int* __restrict__ meta) {
  if (threadIdx.x == 0) {
    int acc = 0;
    for (int e = 0; e < 32; ++e) { meta[e] = acc; acc += (counts[e] + 127) >> 7; }
    meta[32] = acc;
  }
}

// slot assignment: value-deterministic (row placement doesn't change row math)
__global__ __launch_bounds__(256) void build_kernel(const int* __restrict__ sel,
    const float* __restrict__ w4, const int* __restrict__ meta, int* __restrict__ cursor,
    int* __restrict__ tlist, float* __restrict__ wslot, int* __restrict__ pos) {
  int t = blockIdx.x * 256 + threadIdx.x;
  if (t >= T_TOK) return;
#pragma unroll
  for (int k = 0; k < 4; ++k) {
    int e = sel[t * 4 + k];
    int slot = atomicAdd(&cursor[e], 1);
    int g = meta[e] * 128 + slot;
    tlist[g] = t; wslot[g] = w4[t * 4 + k]; pos[t * 4 + k] = g;
  }
}

// ---------------------------------------------------------------------------
// bf16 MFMA GEMM, BM=BN=128, BK=32, 4 waves, B^T [N][K] rows K-contiguous.
// MODE 0: shared GEMM1 dual-B (gate,up), silu(g)*u -> bf16 Hsh[row][z*F_S+col]
// MODE 1: routed GEMM1 sparse (gather rows via tlist), gelu*wslot -> Hr[g][col]
// MODE 2: shared GEMM2 per-expert partial, fp32 spart[z][row][col]
// MODE 3: routed GEMM2 sparse (compact rows), fp32 Y[g][col]
template<int MODE>
__global__ __launch_bounds__(256) void gemm_k(
    const short* __restrict__ A, const short* __restrict__ B, const short* __restrict__ B2,
    short* __restrict__ outH, float* __restrict__ outF, const float* __restrict__ wslot,
    const int* __restrict__ meta, const int* __restrict__ tlist,
    int K, int lda, long zbstride, long ldo, long ocolz, long orowz, long acolz) {
  constexpr int BM = 128, BN = 128;
  constexpr int WM = 64, WN = 64, FM = 4, FN = 4;
  __shared__ short As[BM * 32];
  __shared__ short Bs[BN * 32];
  __shared__ short Bs2[(MODE == 0) ? BN * 32 : 64];

  int tid = threadIdx.x;
  int wv = tid >> 6, lane = tid & 63;
  int wr = wv >> 1, wc = wv & 1;
  int lrow = lane & 15, kg = lane >> 4;
  int z = blockIdx.z;
  int n0 = blockIdx.x * BN;

  int eidx = z;
  int g0 = 0, m0 = blockIdx.y * BM;
  if constexpr (MODE == 1 || MODE == 3) {
    int total = meta[32];
    int ty = blockIdx.y;
    if (ty >= total) return;
    int e = 0;
    while (meta[e + 1] <= ty) ++e;    // <=32 uniform iters
    eidx = e;
    g0 = ty * BM;                     // row_base[e] + local*BM == ty*BM
  }

  const short* Bb = B + (size_t)eidx * zbstride + (size_t)n0 * K;
  const short* B2b = (MODE == 0) ? (B2 + (size_t)eidx * zbstride + (size_t)n0 * K) : B;

  // per-thread staging source pointers (2 rows each: r0 = tid>>2, r1 = r0+64)
  const short* asrc0;
  const short* asrc1;
  if constexpr (MODE == 1) {
    int r0 = tid >> 2;
    int t0 = tlist[g0 + r0], t1 = tlist[g0 + r0 + 64];
    asrc0 = A + (size_t)t0 * lda + (tid & 3) * 8;
    asrc1 = A + (size_t)t1 * lda + (tid & 3) * 8;
  } else {
    const short* Ab = A + (size_t)((MODE == 3) ? g0 : m0) * lda + (MODE == 2 ? acolz * z : 0);
    asrc0 = Ab + (size_t)(tid >> 2) * lda + (tid & 3) * 8;
    asrc1 = asrc0 + (size_t)64 * lda;
  }
  const short* bsrc0 = Bb + (size_t)(tid >> 2) * K + (tid & 3) * 8;
  const short* bsrc1 = bsrc0 + (size_t)64 * K;
  const short* b2src0 = B2b + (size_t)(tid >> 2) * K + (tid & 3) * 8;
  const short* b2src1 = b2src0 + (size_t)64 * K;

  f32x4 acc[FM][FN] = {};
  f32x4 acc2[(MODE == 0) ? FM : 1][(MODE == 0) ? FN : 1] = {};

  for (int kt = 0; kt < K; kt += 32) {
    GLD16(asrc0 + kt, As + wv * 512);
    GLD16(asrc1 + kt, As + wv * 512 + 2048);
    GLD16(bsrc0 + kt, Bs + wv * 512);
    GLD16(bsrc1 + kt, Bs + wv * 512 + 2048);
    if constexpr (MODE == 0) {
      GLD16(b2src0 + kt, Bs2 + wv * 512);
      GLD16(b2src1 + kt, Bs2 + wv * 512 + 2048);
    }
    __syncthreads();
    s16x8 af[FM], bfr[FN], bfr2[(MODE == 0) ? FN : 1];
#pragma unroll
    for (int i = 0; i < FM; ++i)
      af[i] = *(const s16x8*)&As[(wr * WM + i * 16 + lrow) * 32 + kg * 8];
#pragma unroll
    for (int j = 0; j < FN; ++j) {
      bfr[j] = *(const s16x8*)&Bs[(wc * WN + j * 16 + lrow) * 32 + kg * 8];
      if constexpr (MODE == 0)
        bfr2[j] = *(const s16x8*)&Bs2[(wc * WN + j * 16 + lrow) * 32 + kg * 8];
    }
#pragma unroll
    for (int i = 0; i < FM; ++i)
#pragma unroll
      for (int j = 0; j < FN; ++j) {
        acc[i][j] = __builtin_amdgcn_mfma_f32_16x16x32_bf16(af[i], bfr[j], acc[i][j], 0, 0, 0);
        if constexpr (MODE == 0)
          acc2[i][j] = __builtin_amdgcn_mfma_f32_16x16x32_bf16(af[i], bfr2[j], acc2[i][j], 0, 0, 0);
      }
    __syncthreads();
  }
  // epilogue: C/D layout col=lane&15, row=(lane>>4)*4+r  [verified m89]
#pragma unroll
  for (int i = 0; i < FM; ++i) {
#pragma unroll
    for (int r = 0; r < 4; ++r) {
      int rl = wr * WM + i * 16 + kg * 4 + r;
      float wsc = 0.f;
      if constexpr (MODE == 1) wsc = wslot[g0 + rl];
#pragma unroll
      for (int j = 0; j < FN; ++j) {
        int col = n0 + wc * WN + j * 16 + lrow;
        float v = acc[i][j][r];
        if constexpr (MODE == 0) {
          float u = acc2[i][j][r];
          float h = v / (1.f + __expf(-v)) * u;                       // silu(g)*u
          outH[(size_t)(m0 + rl) * ldo + (size_t)z * ocolz + col] = f2bf(h);
        } else if constexpr (MODE == 1) {
          float h = 0.5f * v * (1.f + erff(v * 0.70710678118f)) * wsc; // gelu * gate
          outH[(size_t)(g0 + rl) * ldo + col] = f2bf(h);
        } else if constexpr (MODE == 2) {
          outF[(size_t)z * orowz + (size_t)(m0 + rl) * DHID + col] = v;
        } else {
          outF[(size_t)(g0 + rl) * DHID + col] = v;
        }
      }
    }
  }
}

// ---------------------------------------------------------------------------
// combine: out = mean(spart)/  + gather-sum of Y rows; per-token norms
__global__ __launch_bounds__(256) void combine_kernel(const float* __restrict__ spart,
    const float* __restrict__ Y, const int* __restrict__ pos,
    float* __restrict__ out, float* __restrict__ pnorm) {
  int t = blockIdx.x, tid = threadIdx.x;
  int p0 = pos[t * 4], p1 = pos[t * 4 + 1], p2 = pos[t * 4 + 2], p3 = pos[t * 4 + 3];
  size_t base = (size_t)t * DHID;
  float s2 = 0.f, r2 = 0.f;
  for (int d = tid; d < DHID; d += 256) {
    float s = 0.f;
#pragma unroll
    for (int e = 0; e < 8; ++e) s += spart[(size_t)e * T_TOK * DHID + base + d];
    s *= 0.125f;
    float r = Y[(size_t)p0 * DHID + d] + Y[(size_t)p1 * DHID + d] +
              Y[(size_t)p2 * DHID + d] + Y[(size_t)p3 * DHID + d];
    out[base + d] = s + r;
    s2 += s * s; r2 += r * r;
  }
  for (int o = 32; o > 0; o >>= 1) { s2 += __shfl_down(s2, o); r2 += __shfl_down(r2, o); }
  __shared__ float red[8];
  int wv = tid >> 6, lane = tid & 63;
  if (lane == 0) { red[wv] = s2; red[4 + wv] = r2; }
  __syncthreads();
  if (tid == 0) {
    float st = red[0] + red[1] + red[2] + red[3];
    float rt = red[4] + red[5] + red[6] + red[7];
    pnorm[t] = sqrtf(st);
    pnorm[T_TOK + t] = sqrtf(rt);
  }
}

__global__ __launch_bounds__(256) void finalize_kernel(const int* __restrict__ counts,
    const float* __restrict__ pent, const float* __restrict__ pnorm, float* __restrict__ o) {
  int tid = threadIdx.x;
  float es = 0.f, ss = 0.f, rs = 0.f;
  for (int i = tid; i < T_TOK; i += 256) {
    es += pent[i]; ss += pnorm[i]; rs += pnorm[T_TOK + i];
  }
  float vs = 0.f;
  if (tid < 32) { float d = (float)counts[tid] - 512.f; vs = d * d; }
  for (int off = 32; off > 0; off >>= 1) {
    es += __shfl_down(es, off); ss += __shfl_down(ss, off);
    rs += __shfl_down(rs, off); vs += __shfl_down(vs, off);
  }
  __shared__ float red[16];
  int wv = tid >> 6, lane = tid & 63;
  if (lane == 0) { red[wv] = es; red[4 + wv] = ss; red[8 + wv] = rs; red[12 + wv] = vs; }
  __syncthreads();
  if (tid == 0) {
    es = red[0] + red[1] + red[2] + red[3];
    ss = red[4] + red[5] + red[6] + red[7];
    rs = red[8] + red[9] + red[10] + red[11];
    vs = red[12] + red[13] + red[14] + red[15];
    o[0] = vs / 31.f;                     // load_balance_loss (ddof=1, mean=512 exact)
    o[1] = es / (float)T_TOK;             // router_entropy
    o[2] = fabsf(ss - rs) / (float)T_TOK; // balance_loss
  }
}

// ---------------------------------------------------------------------------
extern "C" void kernel_launch(void* const* d_in, const int* in_sizes, int n_in,
                              void* d_out, int out_size, void* d_ws, size_t ws_size,
                              hipStream_t stream) {
  const float* x   = (const float*)d_in[0];
  const float* swg = (const float*)d_in[1];
  const float* swu = (const float*)d_in[2];
  const float* swd = (const float*)d_in[3];
  const float* rw1 = (const float*)d_in[4];
  const float* rw2 = (const float*)d_in[5];
  const float* rdn = (const float*)d_in[6];
  const float* rup = (const float*)d_in[7];
  float* fout = (float*)d_out;

  // ---- workspace layout ----
  char* w = (char*)d_ws;
  size_t off = 0;
  auto take = [&](size_t bytes) { char* p = w + off; off = (off + bytes + 255) & ~(size_t)255; return p; };
  short* xbf   = (short*)take((size_t)T_TOK * DHID * 2);
  int*   sel   = (int*)  take((size_t)T_TOK * 4 * 4);
  float* w4    = (float*)take((size_t)T_TOK * 4 * 4);
  int*   pos   = (int*)  take((size_t)T_TOK * 4 * 4);
  int*   counts= (int*)  take(32 * 4);
  int*   cursor= (int*)  take(32 * 4);
  int*   meta  = (int*)  take(64 * 4);
  int*   tlist = (int*)  take((size_t)MAXROWS * 4);
  float* wslot = (float*)take((size_t)MAXROWS * 4);
  float* pent  = (float*)take((size_t)T_TOK * 4);
  float* pnorm = (float*)take((size_t)2 * T_TOK * 4);
  float* spart = (float*)take((size_t)NE_S * T_TOK * DHID * 4);   // 100.7 MB
  char*  arena = w + off;

  // arena (phase-overlapped):
  // shared phase:  [wgT 28.3][wuT 28.3][wdT 28.3][Hsh 151]  = 236 MB
  // routed phase:  [Y 62.9][w1T 75.5][w2T 75.5][Hr 62.9]    = 277 MB
  short* wgT = (short*)arena;
  short* wuT = wgT + (size_t)NE_S * F_S * DHID;
  short* wdT = wuT + (size_t)NE_S * F_S * DHID;
  short* Hsh = wdT + (size_t)NE_S * F_S * DHID;
  float* Y   = (float*)arena;
  short* w1T = (short*)(arena + (size_t)MAXROWS * DHID * 4);
  short* w2T = w1T + (size_t)NE_R * F_R * DHID;
  short* Hr  = w2T + (size_t)NE_R * F_R * DHID;

  // ---- setup / router ----
  zero_kernel<<<(MAXROWS + 255) / 256, 256, 0, stream>>>(tlist, wslot, counts, cursor);
  cvt_x_kernel<<<(T_TOK * DHID / 4 + 255) / 256, 256, 0, stream>>>(x, xbf, T_TOK * DHID / 4);
  router_kernel<<<T_TOK, 64, 0, stream>>>(x, rdn, rup, sel, w4, counts, pent);
  meta_kernel<<<1, 64, 0, stream>>>(counts, meta);
  build_kernel<<<T_TOK / 256, 256, 0, stream>>>(sel, w4, meta, cursor, tlist, wslot, pos);

  // ---- shared experts ----
  transpose_cvt<<<dim3(F_S / 32, DHID / 32, NE_S), dim3(32, 8), 0, stream>>>(
      swg, wgT, DHID, F_S, DHID, (long)F_S * DHID);
  transpose_cvt<<<dim3(F_S / 32, DHID / 32, NE_S), dim3(32, 8), 0, stream>>>(
      swu, wuT, DHID, F_S, DHID, (long)F_S * DHID);
  transpose_cvt<<<dim3(DHID / 32, F_S / 32, NE_S), dim3(32, 8), 0, stream>>>(
      swd, wdT, F_S, DHID, (long)F_S, (long)DHID * F_S);
  gemm_k<0><<<dim3(F_S / 128, T_TOK / 128, NE_S), 256, 0, stream>>>(
      xbf, wgT, wuT, Hsh, nullptr, nullptr, nullptr, nullptr,
      DHID, DHID, (long)F_S * DHID, (long)NE_S * F_S, (long)F_S, 0, 0);
  gemm_k<2><<<dim3(DHID / 128, T_TOK / 128, NE_S), 256, 0, stream>>>(
      Hsh, wdT, nullptr, nullptr, spart, nullptr, nullptr, nullptr,
      F_S, NE_S * F_S, (long)DHID * F_S, DHID, 0, (long)T_TOK * DHID, (long)F_S);

  // ---- routed experts (sparse, tile-compacted) ----
  transpose_cvt<<<dim3(F_R / 32, DHID / 32, NE_R), dim3(32, 8), 0, stream>>>(
      rw1, w1T, DHID, F_R, DHID, (long)F_R * DHID);
  transpose_cvt<<<dim3(DHID / 32, F_R / 32, NE_R), dim3(32, 8), 0, stream>>>(
      rw2, w2T, F_R, DHID, (long)F_R, (long)DHID * F_R);
  gemm_k<1><<<dim3(F_R / 128, MAX_TILES, 1), 256, 0, stream>>>(
      xbf, w1T, nullptr, Hr, nullptr, wslot, meta, tlist,
      DHID, DHID, (long)F_R * DHID, (long)F_R, 0, 0, 0);
  gemm_k<3><<<dim3(DHID / 128, MAX_TILES, 1), 256, 0, stream>>>(
      Hr, w2T, nullptr, nullptr, Y, nullptr, meta, tlist,
      F_R, F_R, (long)DHID * F_R, DHID, 0, 0, 0);

  // ---- combine + scalars ----
  combine_kernel<<<T_TOK, 256, 0, stream>>>(spart, Y, pos, fout, pnorm);
  finalize_kernel<<<1, 256, 0, stream>>>(counts, pent, pnorm, fout + (size_t)T_TOK * DHID);
}

// Round 3
// 973.529 us; speedup vs baseline: 2.8546x; 1.3662x over previous
//
#include <hip/hip_runtime.h>
#include <hip/hip_bf16.h>
#include <math.h>

// ---------------------------------------------------------------------------
// MoE round 3: BK=64 + XOR-swizzled LDS (conflict-free ds_read_b128) +
// launch_bounds(256,2) on the dual-B shared GEMM1 (occupancy 1 -> 2 blocks/CU).
// Sparse routed experts, split-K-by-expert shared GEMM2, fp32 router.
// ---------------------------------------------------------------------------

#define T_TOK 4096
#define DHID 768
#define NE_R 32
#define NE_S 8
#define F_S 2304
#define F_R 1536
#define MAXROWS 20480   // 160 tiles * 128
#define MAX_TILES 160

typedef float f32x4 __attribute__((ext_vector_type(4)));
typedef short s16x8 __attribute__((ext_vector_type(8)));

__device__ __forceinline__ short f2bf(float f) {
  union { float f; unsigned u; } v; v.f = f;
  unsigned r = v.u + 0x7fffu + ((v.u >> 16) & 1u);   // RNE
  return (short)(r >> 16);
}

// async global->LDS, 16B per lane, wave-uniform LDS base (per-lane global src OK)
#define GLD16(gsrc, ldst)                                                     \
  __builtin_amdgcn_global_load_lds(                                           \
      (const __attribute__((address_space(1))) void*)(gsrc),                  \
      (__attribute__((address_space(3))) void*)(ldst), 16, 0, 0)

// ---------------------------------------------------------------------------
__global__ __launch_bounds__(256) void cvt_x_kernel(const float* __restrict__ in,
                                                    short* __restrict__ out, int n4) {
  int i = blockIdx.x * 256 + threadIdx.x;
  if (i >= n4) return;
  float4 v = ((const float4*)in)[i];
  short4 o;
  o.x = f2bf(v.x); o.y = f2bf(v.y); o.z = f2bf(v.z); o.w = f2bf(v.w);
  ((short4*)out)[i] = o;
}

// ---------------------------------------------------------------------------
// Batched transpose+convert: out[c*ldo + r] (bf16) = in[r*C + c] (f32)
__global__ __launch_bounds__(256) void transpose_cvt(const float* __restrict__ in,
                                                     short* __restrict__ out,
                                                     int R, int C, long ldo, long out_bstride) {
  __shared__ float tile[32][33];
  int b = blockIdx.z;
  in += (size_t)b * R * C;
  out += (size_t)b * out_bstride;
  int c0 = blockIdx.x * 32, r0 = blockIdx.y * 32;
  int tx = threadIdx.x, ty = threadIdx.y;  // 32 x 8
#pragma unroll
  for (int i = 0; i < 32; i += 8)
    tile[ty + i][tx] = in[(size_t)(r0 + ty + i) * C + (c0 + tx)];
  __syncthreads();
#pragma unroll
  for (int i = 0; i < 32; i += 8)
    out[(size_t)(c0 + ty + i) * ldo + (r0 + tx)] = f2bf(tile[tx][ty + i]);
}

// ---------------------------------------------------------------------------
// Router: fp32, one wave per token. sel[t][4], w4[t][4], counts, entropy.
__global__ __launch_bounds__(64) void router_kernel(const float* __restrict__ x,
    const float* __restrict__ rdown, const float* __restrict__ rup,
    int* __restrict__ sel, float* __restrict__ w4, int* __restrict__ counts,
    float* __restrict__ pent) {
  int t = blockIdx.x;
  int lane = threadIdx.x;
  __shared__ float xs[DHID];
  __shared__ float xrs[64];
  __shared__ float lg[32];
  const float* xt = x + (size_t)t * DHID;
  for (int i = lane; i < DHID; i += 64) xs[i] = xt[i];
  __syncthreads();
  float acc = 0.f;
#pragma unroll 8
  for (int d = 0; d < DHID; ++d) acc += xs[d] * rdown[d * 64 + lane];
  xrs[lane] = acc;
  __syncthreads();
  if (lane < 32) {
    float l = 0.f;
#pragma unroll 8
    for (int r = 0; r < 64; ++r) l += xrs[r] * rup[r * 32 + lane];
    lg[lane] = l;
  }
  __syncthreads();
  if (lane == 0) {
    int si[4]; float sv[4];
    unsigned taken = 0;
    for (int k = 0; k < 4; ++k) {            // top-4, ties -> lowest index
      float best = -3.4e38f; int bi = 0;
      for (int e = 0; e < 32; ++e)
        if (!((taken >> e) & 1u) && lg[e] > best) { best = lg[e]; bi = e; }
      taken |= 1u << bi; si[k] = bi; sv[k] = best;
    }
    float m = sv[0];
    float wv[4]; float zs = 0.f;
    for (int k = 0; k < 4; ++k) { wv[k] = __expf(sv[k] - m); zs += wv[k]; }
    for (int k = 0; k < 4; ++k) {
      sel[t * 4 + k] = si[k];
      w4[t * 4 + k] = wv[k] / zs;
      atomicAdd(&counts[si[k]], 1);
    }
    float Z = 0.f;
    for (int e = 0; e < 32; ++e) Z += __expf(lg[e] - m);
    float ent = 0.f;
    for (int e = 0; e < 32; ++e) {
      float p = __expf(lg[e] - m) / Z;
      ent -= p * logf(p + 1e-10f);
    }
    pent[t] = ent;
  }
}

// ---------------------------------------------------------------------------
__global__ void zero_kernel(int* __restrict__ tlist, float* __restrict__ wslot,
                            int* __restrict__ counts, int* __restrict__ cursor) {
  int i = blockIdx.x * 256 + threadIdx.x;
  if (i < MAXROWS) { tlist[i] = 0; wslot[i] = 0.f; }
  if (i < 32) { counts[i] = 0; cursor[i] = 0; }
}

// meta[e] = tile_base prefix (tiles of 128), meta[32] = total tiles
__global__ void meta_kernel(const int* __restrict__ counts, int* __restrict__ meta) {
  if (threadIdx.x == 0) {
    int acc = 0;
    for (int e = 0; e < 32; ++e) { meta[e] = acc; acc += (counts[e] + 127) >> 7; }
    meta[32] = acc;
  }
}

// slot assignment: value-deterministic (row placement doesn't change row math)
__global__ __launch_bounds__(256) void build_kernel(const int* __restrict__ sel,
    const float* __restrict__ w4, const int* __restrict__ meta, int* __restrict__ cursor,
    int* __restrict__ tlist, float* __restrict__ wslot, int* __restrict__ pos) {
  int t = blockIdx.x * 256 + threadIdx.x;
  if (t >= T_TOK) return;
#pragma unroll
  for (int k = 0; k < 4; ++k) {
    int e = sel[t * 4 + k];
    int slot = atomicAdd(&cursor[e], 1);
    int g = meta[e] * 128 + slot;
    tlist[g] = t; wslot[g] = w4[t * 4 + k]; pos[t * 4 + k] = g;
  }
}

// ---------------------------------------------------------------------------
// bf16 MFMA GEMM, BM=BN=128, BK=64, 4 waves, B^T [N][K] rows K-contiguous.
// LDS XOR-swizzle: phys chunk = logical chunk ^ (row&7), realized by
// pre-swizzled per-lane GLOBAL source (GLD16 dest stays lane-linear) and the
// matching XOR on the ds_read address (rule #21: both-sides involution).
// MODE 0: shared GEMM1 dual-B (gate,up), silu(g)*u -> bf16 Hsh[row][z*F_S+col]
// MODE 1: routed GEMM1 sparse (gather rows via tlist), gelu*wslot -> Hr[g][col]
// MODE 2: shared GEMM2 per-expert partial, fp32 spart[z][row][col]
// MODE 3: routed GEMM2 sparse (compact rows), fp32 Y[g][col]
template<int MODE>
__global__ __launch_bounds__(256, MODE == 0 ? 2 : 1) void gemm_k(
    const short* __restrict__ A, const short* __restrict__ B, const short* __restrict__ B2,
    short* __restrict__ outH, float* __restrict__ outF, const float* __restrict__ wslot,
    const int* __restrict__ meta, const int* __restrict__ tlist,
    int K, int lda, long zbstride, long ldo, long ocolz, long orowz, long acolz) {
  constexpr int BM = 128, BN = 128;
  constexpr int WM = 64, WN = 64, FM = 4, FN = 4;
  __shared__ short As[BM * 64];
  __shared__ short Bs[BN * 64];
  __shared__ short Bs2[(MODE == 0) ? BN * 64 : 64];

  int tid = threadIdx.x;
  int wv = tid >> 6, lane = tid & 63;
  int wr = wv >> 1, wc = wv & 1;
  int lrow = lane & 15, kg = lane >> 4;
  int lrow7 = lrow & 7;
  int z = blockIdx.z;
  int n0 = blockIdx.x * BN;

  int eidx = z;
  int g0 = 0, m0 = blockIdx.y * BM;
  if constexpr (MODE == 1 || MODE == 3) {
    int total = meta[32];
    int ty = blockIdx.y;
    if (ty >= total) return;
    int e = 0;
    while (meta[e + 1] <= ty) ++e;    // <=32 uniform iters
    eidx = e;
    g0 = ty * BM;
  }

  const short* Bb = B + (size_t)eidx * zbstride + (size_t)n0 * K;
  const short* B2b = (MODE == 0) ? (B2 + (size_t)eidx * zbstride + (size_t)n0 * K) : B;

  // staging geometry: round r covers rows r*32 + (tid>>3), 16B chunk (tid&7)
  int srow = tid >> 3;                             // 0..31
  int scol = ((tid & 7) ^ (srow & 7)) * 8;         // swizzled source chunk (shorts)

  const short* asrc[2][2];   // [r>>1][r&1] flattened as [2][2] for unroll safety
  const short* bsrc[4];
  const short* b2src[4];
#pragma unroll
  for (int r = 0; r < 4; ++r) {
    int row = r * 32 + srow;
    const short* ap;
    if constexpr (MODE == 1) {
      int t0 = tlist[g0 + row];
      ap = A + (size_t)t0 * lda + scol;
    } else {
      size_t base_row = (size_t)((MODE == 3) ? g0 : m0) + row;
      ap = A + base_row * lda + (MODE == 2 ? (size_t)acolz * z : 0) + scol;
    }
    asrc[r >> 1][r & 1] = ap;
    bsrc[r] = Bb + (size_t)row * K + scol;
    if constexpr (MODE == 0) b2src[r] = B2b + (size_t)row * K + scol;
  }

  f32x4 acc[FM][FN] = {};
  f32x4 acc2[(MODE == 0) ? FM : 1][(MODE == 0) ? FN : 1] = {};

  for (int kt = 0; kt < K; kt += 64) {
#pragma unroll
    for (int r = 0; r < 4; ++r) {
      GLD16(asrc[r >> 1][r & 1] + kt, As + (r * 32 + wv * 8) * 64);
      GLD16(bsrc[r] + kt, Bs + (r * 32 + wv * 8) * 64);
      if constexpr (MODE == 0)
        GLD16(b2src[r] + kt, Bs2 + (r * 32 + wv * 8) * 64);
    }
    __syncthreads();
#pragma unroll
    for (int ks = 0; ks < 2; ++ks) {
      int pc = ((ks * 4 + kg) ^ lrow7) * 8;        // swizzled chunk offset (shorts)
      s16x8 af[FM], bb[FN];
#pragma unroll
      for (int i = 0; i < FM; ++i)
        af[i] = *(const s16x8*)&As[(wr * WM + i * 16 + lrow) * 64 + pc];
#pragma unroll
      for (int j = 0; j < FN; ++j)
        bb[j] = *(const s16x8*)&Bs[(wc * WN + j * 16 + lrow) * 64 + pc];
#pragma unroll
      for (int i = 0; i < FM; ++i)
#pragma unroll
        for (int j = 0; j < FN; ++j)
          acc[i][j] = __builtin_amdgcn_mfma_f32_16x16x32_bf16(af[i], bb[j], acc[i][j], 0, 0, 0);
      if constexpr (MODE == 0) {
        s16x8 b2[FN];
#pragma unroll
        for (int j = 0; j < FN; ++j)
          b2[j] = *(const s16x8*)&Bs2[(wc * WN + j * 16 + lrow) * 64 + pc];
#pragma unroll
        for (int i = 0; i < FM; ++i)
#pragma unroll
          for (int j = 0; j < FN; ++j)
            acc2[i][j] = __builtin_amdgcn_mfma_f32_16x16x32_bf16(af[i], b2[j], acc2[i][j], 0, 0, 0);
      }
    }
    __syncthreads();
  }
  // epilogue: C/D layout col=lane&15, row=(lane>>4)*4+r  [verified m89]
#pragma unroll
  for (int i = 0; i < FM; ++i) {
#pragma unroll
    for (int r = 0; r < 4; ++r) {
      int rl = wr * WM + i * 16 + kg * 4 + r;
      float wsc = 0.f;
      if constexpr (MODE == 1) wsc = wslot[g0 + rl];
#pragma unroll
      for (int j = 0; j < FN; ++j) {
        int col = n0 + wc * WN + j * 16 + lrow;
        float v = acc[i][j][r];
        if constexpr (MODE == 0) {
          float u = acc2[i][j][r];
          float h = v / (1.f + __expf(-v)) * u;                       // silu(g)*u
          outH[(size_t)(m0 + rl) * ldo + (size_t)z * ocolz + col] = f2bf(h);
        } else if constexpr (MODE == 1) {
          float h = 0.5f * v * (1.f + erff(v * 0.70710678118f)) * wsc; // gelu * gate
          outH[(size_t)(g0 + rl) * ldo + col] = f2bf(h);
        } else if constexpr (MODE == 2) {
          outF[(size_t)z * orowz + (size_t)(m0 + rl) * DHID + col] = v;
        } else {
          outF[(size_t)(g0 + rl) * DHID + col] = v;
        }
      }
    }
  }
}

// ---------------------------------------------------------------------------
// combine: out = mean(spart) + gather-sum of Y rows; per-token norms
__global__ __launch_bounds__(256) void combine_kernel(const float* __restrict__ spart,
    const float* __restrict__ Y, const int* __restrict__ pos,
    float* __restrict__ out, float* __restrict__ pnorm) {
  int t = blockIdx.x, tid = threadIdx.x;
  int p0 = pos[t * 4], p1 = pos[t * 4 + 1], p2 = pos[t * 4 + 2], p3 = pos[t * 4 + 3];
  size_t base = (size_t)t * DHID;
  float s2 = 0.f, r2 = 0.f;
  for (int d = tid; d < DHID; d += 256) {
    float s = 0.f;
#pragma unroll
    for (int e = 0; e < 8; ++e) s += spart[(size_t)e * T_TOK * DHID + base + d];
    s *= 0.125f;
    float r = Y[(size_t)p0 * DHID + d] + Y[(size_t)p1 * DHID + d] +
              Y[(size_t)p2 * DHID + d] + Y[(size_t)p3 * DHID + d];
    out[base + d] = s + r;
    s2 += s * s; r2 += r * r;
  }
  for (int o = 32; o > 0; o >>= 1) { s2 += __shfl_down(s2, o); r2 += __shfl_down(r2, o); }
  __shared__ float red[8];
  int wv = tid >> 6, lane = tid & 63;
  if (lane == 0) { red[wv] = s2; red[4 + wv] = r2; }
  __syncthreads();
  if (tid == 0) {
    float st = red[0] + red[1] + red[2] + red[3];
    float rt = red[4] + red[5] + red[6] + red[7];
    pnorm[t] = sqrtf(st);
    pnorm[T_TOK + t] = sqrtf(rt);
  }
}

__global__ __launch_bounds__(256) void finalize_kernel(const int* __restrict__ counts,
    const float* __restrict__ pent, const float* __restrict__ pnorm, float* __restrict__ o) {
  int tid = threadIdx.x;
  float es = 0.f, ss = 0.f, rs = 0.f;
  for (int i = tid; i < T_TOK; i += 256) {
    es += pent[i]; ss += pnorm[i]; rs += pnorm[T_TOK + i];
  }
  float vs = 0.f;
  if (tid < 32) { float d = (float)counts[tid] - 512.f; vs = d * d; }
  for (int off = 32; off > 0; off >>= 1) {
    es += __shfl_down(es, off); ss += __shfl_down(ss, off);
    rs += __shfl_down(rs, off); vs += __shfl_down(vs, off);
  }
  __shared__ float red[16];
  int wv = tid >> 6, lane = tid & 63;
  if (lane == 0) { red[wv] = es; red[4 + wv] = ss; red[8 + wv] = rs; red[12 + wv] = vs; }
  __syncthreads();
  if (tid == 0) {
    es = red[0] + red[1] + red[2] + red[3];
    ss = red[4] + red[5] + red[6] + red[7];
    rs = red[8] + red[9] + red[10] + red[11];
    vs = red[12] + red[13] + red[14] + red[15];
    o[0] = vs / 31.f;                     // load_balance_loss (ddof=1, mean=512 exact)
    o[1] = es / (float)T_TOK;             // router_entropy
    o[2] = fabsf(ss - rs) / (float)T_TOK; // balance_loss
  }
}

// ---------------------------------------------------------------------------
extern "C" void kernel_launch(void* const* d_in, const int* in_sizes, int n_in,
                              void* d_out, int out_size, void* d_ws, size_t ws_size,
                              hipStream_t stream) {
  const float* x   = (const float*)d_in[0];
  const float* swg = (const float*)d_in[1];
  const float* swu = (const float*)d_in[2];
  const float* swd = (const float*)d_in[3];
  const float* rw1 = (const float*)d_in[4];
  const float* rw2 = (const float*)d_in[5];
  const float* rdn = (const float*)d_in[6];
  const float* rup = (const float*)d_in[7];
  float* fout = (float*)d_out;

  // ---- workspace layout ----
  char* w = (char*)d_ws;
  size_t off = 0;
  auto take = [&](size_t bytes) { char* p = w + off; off = (off + bytes + 255) & ~(size_t)255; return p; };
  short* xbf   = (short*)take((size_t)T_TOK * DHID * 2);
  int*   sel   = (int*)  take((size_t)T_TOK * 4 * 4);
  float* w4    = (float*)take((size_t)T_TOK * 4 * 4);
  int*   pos   = (int*)  take((size_t)T_TOK * 4 * 4);
  int*   counts= (int*)  take(32 * 4);
  int*   cursor= (int*)  take(32 * 4);
  int*   meta  = (int*)  take(64 * 4);
  int*   tlist = (int*)  take((size_t)MAXROWS * 4);
  float* wslot = (float*)take((size_t)MAXROWS * 4);
  float* pent  = (float*)take((size_t)T_TOK * 4);
  float* pnorm = (float*)take((size_t)2 * T_TOK * 4);
  float* spart = (float*)take((size_t)NE_S * T_TOK * DHID * 4);   // 100.7 MB
  char*  arena = w + off;

  // arena (phase-overlapped):
  // shared phase:  [wgT 28.3][wuT 28.3][wdT 28.3][Hsh 151]  = 236 MB
  // routed phase:  [Y 62.9][w1T 75.5][w2T 75.5][Hr 62.9]    = 277 MB
  short* wgT = (short*)arena;
  short* wuT = wgT + (size_t)NE_S * F_S * DHID;
  short* wdT = wuT + (size_t)NE_S * F_S * DHID;
  short* Hsh = wdT + (size_t)NE_S * F_S * DHID;
  float* Y   = (float*)arena;
  short* w1T = (short*)(arena + (size_t)MAXROWS * DHID * 4);
  short* w2T = w1T + (size_t)NE_R * F_R * DHID;
  short* Hr  = w2T + (size_t)NE_R * F_R * DHID;

  // ---- setup / router ----
  zero_kernel<<<(MAXROWS + 255) / 256, 256, 0, stream>>>(tlist, wslot, counts, cursor);
  cvt_x_kernel<<<(T_TOK * DHID / 4 + 255) / 256, 256, 0, stream>>>(x, xbf, T_TOK * DHID / 4);
  router_kernel<<<T_TOK, 64, 0, stream>>>(x, rdn, rup, sel, w4, counts, pent);
  meta_kernel<<<1, 64, 0, stream>>>(counts, meta);
  build_kernel<<<T_TOK / 256, 256, 0, stream>>>(sel, w4, meta, cursor, tlist, wslot, pos);

  // ---- shared experts ----
  transpose_cvt<<<dim3(F_S / 32, DHID / 32, NE_S), dim3(32, 8), 0, stream>>>(
      swg, wgT, DHID, F_S, DHID, (long)F_S * DHID);
  transpose_cvt<<<dim3(F_S / 32, DHID / 32, NE_S), dim3(32, 8), 0, stream>>>(
      swu, wuT, DHID, F_S, DHID, (long)F_S * DHID);
  transpose_cvt<<<dim3(DHID / 32, F_S / 32, NE_S), dim3(32, 8), 0, stream>>>(
      swd, wdT, F_S, DHID, (long)F_S, (long)DHID * F_S);
  gemm_k<0><<<dim3(F_S / 128, T_TOK / 128, NE_S), 256, 0, stream>>>(
      xbf, wgT, wuT, Hsh, nullptr, nullptr, nullptr, nullptr,
      DHID, DHID, (long)F_S * DHID, (long)NE_S * F_S, (long)F_S, 0, 0);
  gemm_k<2><<<dim3(DHID / 128, T_TOK / 128, NE_S), 256, 0, stream>>>(
      Hsh, wdT, nullptr, nullptr, spart, nullptr, nullptr, nullptr,
      F_S, NE_S * F_S, (long)DHID * F_S, DHID, 0, (long)T_TOK * DHID, (long)F_S);

  // ---- routed experts (sparse, tile-compacted) ----
  transpose_cvt<<<dim3(F_R / 32, DHID / 32, NE_R), dim3(32, 8), 0, stream>>>(
      rw1, w1T, DHID, F_R, DHID, (long)F_R * DHID);
  transpose_cvt<<<dim3(DHID / 32, F_R / 32, NE_R), dim3(32, 8), 0, stream>>>(
      rw2, w2T, F_R, DHID, (long)F_R, (long)DHID * F_R);
  gemm_k<1><<<dim3(F_R / 128, MAX_TILES, 1), 256, 0, stream>>>(
      xbf, w1T, nullptr, Hr, nullptr, wslot, meta, tlist,
      DHID, DHID, (long)F_R * DHID, (long)F_R, 0, 0, 0);
  gemm_k<3><<<dim3(DHID / 128, MAX_TILES, 1), 256, 0, stream>>>(
      Hr, w2T, nullptr, nullptr, Y, nullptr, meta, tlist,
      F_R, F_R, (long)DHID * F_R, DHID, 0, 0, 0);

  // ---- combine + scalars ----
  combine_kernel<<<T_TOK, 256, 0, stream>>>(spart, Y, pos, fout, pnorm);
  finalize_kernel<<<1, 256, 0, stream>>>(counts, pent, pnorm, fout + (size_t)T_TOK * DHID);
}

// Round 5
// 940.469 us; speedup vs baseline: 2.9549x; 1.0352x over previous
//
#include <hip/hip_runtime.h>
#include <hip/hip_bf16.h>
#include <math.h>

// ---------------------------------------------------------------------------
// MoE round 5: round 4 (32x32x16 MFMA, XCD swizzle, 2-experts/block MODE2)
// with the transpose ordering bug fixed: transposes split per phase so the
// phase-overlapped arena never clobbers a live buffer (round-3 ordering).
// ---------------------------------------------------------------------------

#define T_TOK 4096
#define DHID 768
#define NE_R 32
#define NE_S 8
#define F_S 2304
#define F_R 1536
#define MAXROWS 20480   // 160 tiles * 128
#define MAX_TILES 160

typedef float f32x16 __attribute__((ext_vector_type(16)));
typedef short s16x8 __attribute__((ext_vector_type(8)));

__device__ __forceinline__ short f2bf(float f) {
  union { float f; unsigned u; } v; v.f = f;
  unsigned r = v.u + 0x7fffu + ((v.u >> 16) & 1u);   // RNE
  return (short)(r >> 16);
}

// async global->LDS, 16B per lane, wave-uniform LDS base (per-lane global src OK)
#define GLD16(gsrc, ldst)                                                     \
  __builtin_amdgcn_global_load_lds(                                           \
      (const __attribute__((address_space(1))) void*)(gsrc),                  \
      (__attribute__((address_space(3))) void*)(ldst), 16, 0, 0)

// ---------------------------------------------------------------------------
// x fp32 -> bf16 (vectorized) + zero-init of routing scratch
__global__ __launch_bounds__(256) void cvt_x_kernel(const float* __restrict__ in,
    short* __restrict__ out, int* __restrict__ tlist, float* __restrict__ wslot,
    int* __restrict__ counts, int* __restrict__ cursor) {
  int i = blockIdx.x * 256 + threadIdx.x;
  if (i < T_TOK * DHID / 4) {
    float4 v = ((const float4*)in)[i];
    short4 o;
    o.x = f2bf(v.x); o.y = f2bf(v.y); o.z = f2bf(v.z); o.w = f2bf(v.w);
    ((short4*)out)[i] = o;
  }
  if (i < MAXROWS) { tlist[i] = 0; wslot[i] = 0.f; }
  if (i < 32) { counts[i] = 0; cursor[i] = 0; }
}

// ---------------------------------------------------------------------------
// Shared-expert weight transposes (swg, swu, swd). out[c*ldo+r] = in[r*C+c].
// MUST run before the shared GEMMs and may NOT touch the routed arena.
__global__ __launch_bounds__(256) void transpose_shared(
    const float* __restrict__ swg, const float* __restrict__ swu,
    const float* __restrict__ swd, short* __restrict__ wgT,
    short* __restrict__ wuT, short* __restrict__ wdT) {
  int bid = blockIdx.x;
  const float* in; short* out; int R, C, nbx; long ldo;
  if (bid < 13824)      { in = swg; out = wgT; R = DHID; C = F_S; ldo = DHID; nbx = 72; }
  else if (bid < 27648) { bid -= 13824; in = swu; out = wuT; R = DHID; C = F_S; ldo = DHID; nbx = 72; }
  else                  { bid -= 27648; in = swd; out = wdT; R = F_S; C = DHID; ldo = F_S; nbx = 24; }
  int per = nbx * (R / 32);
  int b = bid / per, rem = bid % per;
  int c0 = (rem % nbx) * 32, r0 = (rem / nbx) * 32;
  in  += (size_t)b * R * C;
  out += (size_t)b * R * C;
  int tx = threadIdx.x & 31, ty = threadIdx.x >> 5;  // 32 x 8
  __shared__ float tile[32][33];
#pragma unroll
  for (int i = 0; i < 32; i += 8)
    tile[ty + i][tx] = in[(size_t)(r0 + ty + i) * C + (c0 + tx)];
  __syncthreads();
#pragma unroll
  for (int i = 0; i < 32; i += 8)
    out[(size_t)(c0 + ty + i) * ldo + (r0 + tx)] = f2bf(tile[tx][ty + i]);
}

// Routed-expert weight transposes (rw1, rw2). MUST run only after the shared
// GEMMs complete (w1T/w2T overlap the then-dead wdT/Hsh regions).
__global__ __launch_bounds__(256) void transpose_routed(
    const float* __restrict__ rw1, const float* __restrict__ rw2,
    short* __restrict__ w1T, short* __restrict__ w2T) {
  int bid = blockIdx.x;
  const float* in; short* out; int R, C, nbx; long ldo;
  if (bid < 36864) { in = rw1; out = w1T; R = DHID; C = F_R; ldo = DHID; nbx = 48; }
  else             { bid -= 36864; in = rw2; out = w2T; R = F_R; C = DHID; ldo = F_R; nbx = 24; }
  int per = nbx * (R / 32);
  int b = bid / per, rem = bid % per;
  int c0 = (rem % nbx) * 32, r0 = (rem / nbx) * 32;
  in  += (size_t)b * R * C;
  out += (size_t)b * R * C;
  int tx = threadIdx.x & 31, ty = threadIdx.x >> 5;  // 32 x 8
  __shared__ float tile[32][33];
#pragma unroll
  for (int i = 0; i < 32; i += 8)
    tile[ty + i][tx] = in[(size_t)(r0 + ty + i) * C + (c0 + tx)];
  __syncthreads();
#pragma unroll
  for (int i = 0; i < 32; i += 8)
    out[(size_t)(c0 + ty + i) * ldo + (r0 + tx)] = f2bf(tile[tx][ty + i]);
}

// ---------------------------------------------------------------------------
// Router: fp32, one wave per token. sel[t][4], w4[t][4], counts, entropy.
__global__ __launch_bounds__(64) void router_kernel(const float* __restrict__ x,
    const float* __restrict__ rdown, const float* __restrict__ rup,
    int* __restrict__ sel, float* __restrict__ w4, int* __restrict__ counts,
    float* __restrict__ pent) {
  int t = blockIdx.x;
  int lane = threadIdx.x;
  __shared__ float xs[DHID];
  __shared__ float xrs[64];
  __shared__ float lg[32];
  const float* xt = x + (size_t)t * DHID;
  for (int i = lane; i < DHID; i += 64) xs[i] = xt[i];
  __syncthreads();
  float acc = 0.f;
#pragma unroll 8
  for (int d = 0; d < DHID; ++d) acc += xs[d] * rdown[d * 64 + lane];
  xrs[lane] = acc;
  __syncthreads();
  if (lane < 32) {
    float l = 0.f;
#pragma unroll 8
    for (int r = 0; r < 64; ++r) l += xrs[r] * rup[r * 32 + lane];
    lg[lane] = l;
  }
  __syncthreads();
  if (lane == 0) {
    int si[4]; float sv[4];
    unsigned taken = 0;
    for (int k = 0; k < 4; ++k) {            // top-4, ties -> lowest index
      float best = -3.4e38f; int bi = 0;
      for (int e = 0; e < 32; ++e)
        if (!((taken >> e) & 1u) && lg[e] > best) { best = lg[e]; bi = e; }
      taken |= 1u << bi; si[k] = bi; sv[k] = best;
    }
    float m = sv[0];
    float wv[4]; float zs = 0.f;
    for (int k = 0; k < 4; ++k) { wv[k] = __expf(sv[k] - m); zs += wv[k]; }
    for (int k = 0; k < 4; ++k) {
      sel[t * 4 + k] = si[k];
      w4[t * 4 + k] = wv[k] / zs;
      atomicAdd(&counts[si[k]], 1);
    }
    float Z = 0.f;
    for (int e = 0; e < 32; ++e) Z += __expf(lg[e] - m);
    float ent = 0.f;
    for (int e = 0; e < 32; ++e) {
      float p = __expf(lg[e] - m) / Z;
      ent -= p * logf(p + 1e-10f);
    }
    pent[t] = ent;
  }
}

// meta[e] = tile_base prefix (tiles of 128), meta[32] = total tiles
__global__ void meta_kernel(const int* __restrict__ counts, int* __restrict__ meta) {
  if (threadIdx.x == 0) {
    int acc = 0;
    for (int e = 0; e < 32; ++e) { meta[e] = acc; acc += (counts[e] + 127) >> 7; }
    meta[32] = acc;
  }
}

// slot assignment: value-deterministic (row placement doesn't change row math)
__global__ __launch_bounds__(256) void build_kernel(const int* __restrict__ sel,
    const float* __restrict__ w4, const int* __restrict__ meta, int* __restrict__ cursor,
    int* __restrict__ tlist, float* __restrict__ wslot, int* __restrict__ pos) {
  int t = blockIdx.x * 256 + threadIdx.x;
  if (t >= T_TOK) return;
#pragma unroll
  for (int k = 0; k < 4; ++k) {
    int e = sel[t * 4 + k];
    int slot = atomicAdd(&cursor[e], 1);
    int g = meta[e] * 128 + slot;
    tlist[g] = t; wslot[g] = w4[t * 4 + k]; pos[t * 4 + k] = g;
  }
}

// ---------------------------------------------------------------------------
// bf16 MFMA GEMM, BM=BN=128, BK=64, 4 waves (2Mx2N, wave tile 64x64),
// v_mfma_f32_32x32x16_bf16. LDS XOR-swizzle: phys chunk = logical ^ (row&7),
// staged via pre-swizzled global source (rule #21 involution).
// MODE 0: shared GEMM1 dual-B (gate,up), silu(g)*u -> bf16 Hsh  [+XCD swizzle]
// MODE 1: routed GEMM1 sparse gather, gelu*wslot -> bf16 Hr
// MODE 2: shared GEMM2, 2 experts/block accumulated, fp32 spart [+XCD swizzle]
// MODE 3: routed GEMM2 sparse, fp32 Y
template<int MODE>
__global__ __launch_bounds__(256, MODE == 0 ? 2 : 3) void gemm_k(
    const short* __restrict__ A, const short* __restrict__ B, const short* __restrict__ B2,
    short* __restrict__ outH, float* __restrict__ outF, const float* __restrict__ wslot,
    const int* __restrict__ meta, const int* __restrict__ tlist,
    int K, int lda, long zbstride, long ldo, long ocolz, long orowz, long acolz) {
  constexpr int BM = 128, BN = 128;
  __shared__ short As[BM * 64];
  __shared__ short Bs[BN * 64];
  __shared__ short Bs2[(MODE == 0) ? BN * 64 : 64];

  int tid = threadIdx.x;
  int wv = tid >> 6, lane = tid & 63;
  int wr = wv >> 1, wc = wv & 1;
  int lr = lane & 31, kh = lane >> 5;   // 32x32 frag: row=lane&31, khalf=lane>>5
  int z = blockIdx.z;

  int bx = blockIdx.x, by = blockIdx.y;
  if constexpr (MODE == 0 || MODE == 2) {
    // XCD-aware swizzle: give each XCD a contiguous N-slice (B-panel L2-hot).
    int gx = gridDim.x, gy = gridDim.y;
    int nwg = gx * gy;                   // 576 (MODE0) / 192 (MODE2), %8==0
    int orig = by * gx + bx;
    int swz = (orig & 7) * (nwg >> 3) + (orig >> 3);
    bx = swz / gy; by = swz % gy;
  }
  int n0 = bx * BN;

  int eidx = z;
  int g0 = 0, m0 = by * BM;
  if constexpr (MODE == 1 || MODE == 3) {
    int total = meta[32];
    int ty = blockIdx.y;
    if (ty >= total) return;
    int e = 0;
    while (meta[e + 1] <= ty) ++e;    // <=32 uniform iters
    eidx = e;
    g0 = ty * BM;
  }

  // staging geometry: round r covers rows r*32 + (tid>>3), 16B chunk (tid&7)
  int srow = tid >> 3;                             // 0..31
  int scol = ((tid & 7) ^ (srow & 7)) * 8;         // swizzled source chunk (shorts)

  f32x16 acc[2][2] = {};
  f32x16 acc2[(MODE == 0) ? 2 : 1][(MODE == 0) ? 2 : 1] = {};

  constexpr int EPB = (MODE == 2) ? 2 : 1;         // experts per block
#pragma unroll 1
  for (int ei = 0; ei < EPB; ++ei) {
    int e = (MODE == 2) ? (z * 2 + ei) : eidx;
    const short* Bb = B + (size_t)e * zbstride + (size_t)n0 * K;
    const short* B2b = (MODE == 0) ? (B2 + (size_t)e * zbstride + (size_t)n0 * K) : B;

    const short *as0, *as1, *as2, *as3;
    {
      auto arow = [&](int row) -> const short* {
        if constexpr (MODE == 1) {
          return A + (size_t)tlist[g0 + row] * lda + scol;
        } else if constexpr (MODE == 2) {
          return A + ((size_t)(m0 + row)) * lda + (size_t)e * acolz + scol;
        } else if constexpr (MODE == 3) {
          return A + ((size_t)(g0 + row)) * lda + scol;
        } else {
          return A + ((size_t)(m0 + row)) * lda + scol;
        }
      };
      as0 = arow(srow); as1 = arow(32 + srow); as2 = arow(64 + srow); as3 = arow(96 + srow);
    }
    const short* bs0 = Bb + (size_t)srow * K + scol;
    const short* bs1 = bs0 + (size_t)32 * K;
    const short* bs2 = bs0 + (size_t)64 * K;
    const short* bs3 = bs0 + (size_t)96 * K;
    const short* c2s0 = B2b + (size_t)srow * K + scol;
    const short* c2s1 = c2s0 + (size_t)32 * K;
    const short* c2s2 = c2s0 + (size_t)64 * K;
    const short* c2s3 = c2s0 + (size_t)96 * K;

    for (int kt = 0; kt < K; kt += 64) {
      GLD16(as0 + kt, As + (0 * 32 + wv * 8) * 64);
      GLD16(as1 + kt, As + (1 * 32 + wv * 8) * 64);
      GLD16(as2 + kt, As + (2 * 32 + wv * 8) * 64);
      GLD16(as3 + kt, As + (3 * 32 + wv * 8) * 64);
      GLD16(bs0 + kt, Bs + (0 * 32 + wv * 8) * 64);
      GLD16(bs1 + kt, Bs + (1 * 32 + wv * 8) * 64);
      GLD16(bs2 + kt, Bs + (2 * 32 + wv * 8) * 64);
      GLD16(bs3 + kt, Bs + (3 * 32 + wv * 8) * 64);
      if constexpr (MODE == 0) {
        GLD16(c2s0 + kt, Bs2 + (0 * 32 + wv * 8) * 64);
        GLD16(c2s1 + kt, Bs2 + (1 * 32 + wv * 8) * 64);
        GLD16(c2s2 + kt, Bs2 + (2 * 32 + wv * 8) * 64);
        GLD16(c2s3 + kt, Bs2 + (3 * 32 + wv * 8) * 64);
      }
      __syncthreads();
#pragma unroll
      for (int kq = 0; kq < 4; ++kq) {            // 4 x K=16 per BK=64
        int pc = ((kq * 2 + kh) ^ (lr & 7)) * 8;  // swizzled chunk (shorts)
        s16x8 af[2], bb[2];
#pragma unroll
        for (int mi = 0; mi < 2; ++mi)
          af[mi] = *(const s16x8*)&As[(wr * 64 + mi * 32 + lr) * 64 + pc];
#pragma unroll
        for (int nj = 0; nj < 2; ++nj)
          bb[nj] = *(const s16x8*)&Bs[(wc * 64 + nj * 32 + lr) * 64 + pc];
#pragma unroll
        for (int mi = 0; mi < 2; ++mi)
#pragma unroll
          for (int nj = 0; nj < 2; ++nj)
            acc[mi][nj] = __builtin_amdgcn_mfma_f32_32x32x16_bf16(af[mi], bb[nj], acc[mi][nj], 0, 0, 0);
        if constexpr (MODE == 0) {
          s16x8 b2[2];
#pragma unroll
          for (int nj = 0; nj < 2; ++nj)
            b2[nj] = *(const s16x8*)&Bs2[(wc * 64 + nj * 32 + lr) * 64 + pc];
#pragma unroll
          for (int mi = 0; mi < 2; ++mi)
#pragma unroll
            for (int nj = 0; nj < 2; ++nj)
              acc2[mi][nj] = __builtin_amdgcn_mfma_f32_32x32x16_bf16(af[mi], b2[nj], acc2[mi][nj], 0, 0, 0);
        }
      }
      __syncthreads();
    }
  }

  // epilogue: 32x32 C/D layout col=lane&31, row=(reg&3)+8*(reg>>2)+4*(lane>>5)
#pragma unroll
  for (int mi = 0; mi < 2; ++mi) {
#pragma unroll
    for (int rg = 0; rg < 16; ++rg) {
      int rl = wr * 64 + mi * 32 + (rg & 3) + 8 * (rg >> 2) + 4 * kh;
      float wsc = 0.f;
      if constexpr (MODE == 1) wsc = wslot[g0 + rl];
#pragma unroll
      for (int nj = 0; nj < 2; ++nj) {
        int col = n0 + wc * 64 + nj * 32 + lr;
        float v = acc[mi][nj][rg];
        if constexpr (MODE == 0) {
          float u = acc2[mi][nj][rg];
          float h = v / (1.f + __expf(-v)) * u;                       // silu(g)*u
          outH[(size_t)(m0 + rl) * ldo + (size_t)z * ocolz + col] = f2bf(h);
        } else if constexpr (MODE == 1) {
          float h = 0.5f * v * (1.f + erff(v * 0.70710678118f)) * wsc; // gelu * gate
          outH[(size_t)(g0 + rl) * ldo + col] = f2bf(h);
        } else if constexpr (MODE == 2) {
          outF[(size_t)z * orowz + (size_t)(m0 + rl) * DHID + col] = v;
        } else {
          outF[(size_t)(g0 + rl) * DHID + col] = v;
        }
      }
    }
  }
}

// ---------------------------------------------------------------------------
// combine: out = mean(4 partials, each = 2 experts) + gather-sum of Y rows
__global__ __launch_bounds__(256) void combine_kernel(const float* __restrict__ spart,
    const float* __restrict__ Y, const int* __restrict__ pos,
    float* __restrict__ out, float* __restrict__ pnorm) {
  int t = blockIdx.x, tid = threadIdx.x;
  int p0 = pos[t * 4], p1 = pos[t * 4 + 1], p2 = pos[t * 4 + 2], p3 = pos[t * 4 + 3];
  size_t base = (size_t)t * DHID;
  float s2 = 0.f, r2 = 0.f;
  for (int d = tid; d < DHID; d += 256) {
    float s = 0.f;
#pragma unroll
    for (int e = 0; e < 4; ++e) s += spart[(size_t)e * T_TOK * DHID + base + d];
    s *= 0.125f;
    float r = Y[(size_t)p0 * DHID + d] + Y[(size_t)p1 * DHID + d] +
              Y[(size_t)p2 * DHID + d] + Y[(size_t)p3 * DHID + d];
    out[base + d] = s + r;
    s2 += s * s; r2 += r * r;
  }
  for (int o = 32; o > 0; o >>= 1) { s2 += __shfl_down(s2, o); r2 += __shfl_down(r2, o); }
  __shared__ float red[8];
  int wv = tid >> 6, lane = tid & 63;
  if (lane == 0) { red[wv] = s2; red[4 + wv] = r2; }
  __syncthreads();
  if (tid == 0) {
    float st = red[0] + red[1] + red[2] + red[3];
    float rt = red[4] + red[5] + red[6] + red[7];
    pnorm[t] = sqrtf(st);
    pnorm[T_TOK + t] = sqrtf(rt);
  }
}

__global__ __launch_bounds__(256) void finalize_kernel(const int* __restrict__ counts,
    const float* __restrict__ pent, const float* __restrict__ pnorm, float* __restrict__ o) {
  int tid = threadIdx.x;
  float es = 0.f, ss = 0.f, rs = 0.f;
  for (int i = tid; i < T_TOK; i += 256) {
    es += pent[i]; ss += pnorm[i]; rs += pnorm[T_TOK + i];
  }
  float vs = 0.f;
  if (tid < 32) { float d = (float)counts[tid] - 512.f; vs = d * d; }
  for (int off = 32; off > 0; off >>= 1) {
    es += __shfl_down(es, off); ss += __shfl_down(ss, off);
    rs += __shfl_down(rs, off); vs += __shfl_down(vs, off);
  }
  __shared__ float red[16];
  int wv = tid >> 6, lane = tid & 63;
  if (lane == 0) { red[wv] = es; red[4 + wv] = ss; red[8 + wv] = rs; red[12 + wv] = vs; }
  __syncthreads();
  if (tid == 0) {
    es = red[0] + red[1] + red[2] + red[3];
    ss = red[4] + red[5] + red[6] + red[7];
    rs = red[8] + red[9] + red[10] + red[11];
    vs = red[12] + red[13] + red[14] + red[15];
    o[0] = vs / 31.f;                     // load_balance_loss (ddof=1, mean=512 exact)
    o[1] = es / (float)T_TOK;             // router_entropy
    o[2] = fabsf(ss - rs) / (float)T_TOK; // balance_loss
  }
}

// ---------------------------------------------------------------------------
extern "C" void kernel_launch(void* const* d_in, const int* in_sizes, int n_in,
                              void* d_out, int out_size, void* d_ws, size_t ws_size,
                              hipStream_t stream) {
  const float* x   = (const float*)d_in[0];
  const float* swg = (const float*)d_in[1];
  const float* swu = (const float*)d_in[2];
  const float* swd = (const float*)d_in[3];
  const float* rw1 = (const float*)d_in[4];
  const float* rw2 = (const float*)d_in[5];
  const float* rdn = (const float*)d_in[6];
  const float* rup = (const float*)d_in[7];
  float* fout = (float*)d_out;

  // ---- workspace layout ----
  char* w = (char*)d_ws;
  size_t off = 0;
  auto take = [&](size_t bytes) { char* p = w + off; off = (off + bytes + 255) & ~(size_t)255; return p; };
  short* xbf   = (short*)take((size_t)T_TOK * DHID * 2);
  int*   sel   = (int*)  take((size_t)T_TOK * 4 * 4);
  float* w4    = (float*)take((size_t)T_TOK * 4 * 4);
  int*   pos   = (int*)  take((size_t)T_TOK * 4 * 4);
  int*   counts= (int*)  take(32 * 4);
  int*   cursor= (int*)  take(32 * 4);
  int*   meta  = (int*)  take(64 * 4);
  int*   tlist = (int*)  take((size_t)MAXROWS * 4);
  float* wslot = (float*)take((size_t)MAXROWS * 4);
  float* pent  = (float*)take((size_t)T_TOK * 4);
  float* pnorm = (float*)take((size_t)2 * T_TOK * 4);
  float* spart = (float*)take((size_t)4 * T_TOK * DHID * 4);   // 50.3 MB
  char*  arena = w + off;

  // arena (phase-overlapped; LIFETIME ORDER MATTERS):
  // shared phase:  [wgT 28.3][wuT 28.3][wdT 28.3][Hsh 151]  = 236 MB
  // routed phase:  [Y 62.9][w1T 75.5][w2T 75.5][Hr 62.9]    = 277 MB
  // transpose_routed (w1T,w2T) must run AFTER the shared GEMMs (overlap wdT/Hsh).
  short* wgT = (short*)arena;
  short* wuT = wgT + (size_t)NE_S * F_S * DHID;
  short* wdT = wuT + (size_t)NE_S * F_S * DHID;
  short* Hsh = wdT + (size_t)NE_S * F_S * DHID;
  float* Y   = (float*)arena;
  short* w1T = (short*)(arena + (size_t)MAXROWS * DHID * 4);
  short* w2T = w1T + (size_t)NE_R * F_R * DHID;
  short* Hr  = w2T + (size_t)NE_R * F_R * DHID;

  // ---- setup / router ----
  cvt_x_kernel<<<(T_TOK * DHID / 4 + 255) / 256, 256, 0, stream>>>(x, xbf, tlist, wslot, counts, cursor);
  router_kernel<<<T_TOK, 64, 0, stream>>>(x, rdn, rup, sel, w4, counts, pent);
  meta_kernel<<<1, 64, 0, stream>>>(counts, meta);
  build_kernel<<<T_TOK / 256, 256, 0, stream>>>(sel, w4, meta, cursor, tlist, wslot, pos);

  // ---- shared experts ----
  transpose_shared<<<41472, 256, 0, stream>>>(swg, swu, swd, wgT, wuT, wdT);
  gemm_k<0><<<dim3(F_S / 128, T_TOK / 128, NE_S), 256, 0, stream>>>(
      xbf, wgT, wuT, Hsh, nullptr, nullptr, nullptr, nullptr,
      DHID, DHID, (long)F_S * DHID, (long)NE_S * F_S, (long)F_S, 0, 0);
  gemm_k<2><<<dim3(DHID / 128, T_TOK / 128, NE_S / 2), 256, 0, stream>>>(
      Hsh, wdT, nullptr, nullptr, spart, nullptr, nullptr, nullptr,
      F_S, NE_S * F_S, (long)DHID * F_S, DHID, 0, (long)T_TOK * DHID, (long)F_S);

  // ---- routed experts (sparse, tile-compacted) ----
  transpose_routed<<<73728, 256, 0, stream>>>(rw1, rw2, w1T, w2T);
  gemm_k<1><<<dim3(F_R / 128, MAX_TILES, 1), 256, 0, stream>>>(
      xbf, w1T, nullptr, Hr, nullptr, wslot, meta, tlist,
      DHID, DHID, (long)F_R * DHID, (long)F_R, 0, 0, 0);
  gemm_k<3><<<dim3(DHID / 128, MAX_TILES, 1), 256, 0, stream>>>(
      Hr, w2T, nullptr, nullptr, Y, nullptr, meta, tlist,
      F_R, F_R, (long)DHID * F_R, DHID, 0, 0, 0);

  // ---- combine + scalars ----
  combine_kernel<<<T_TOK, 256, 0, stream>>>(spart, Y, pos, fout, pnorm);
  finalize_kernel<<<1, 256, 0, stream>>>(counts, pent, pnorm, fout + (size_t)T_TOK * DHID);
}

// Round 6
// 906.600 us; speedup vs baseline: 3.0653x; 1.0374x over previous
//
#include <hip/hip_runtime.h>
#include <hip/hip_bf16.h>
#include <math.h>

// ---------------------------------------------------------------------------
// MoE round 6: revert MFMA to the proven 16x16x32 core (R3: 0 bank conflicts,
// 263us) -- the 32x32x16 switch regressed (+2.1e7 conflicts, +30us, compiler
// codegen artifact). Keep R5's verified wins: XCD N-slice swizzle (FETCH
// 537->324MB), MODE2 2-experts/block, split transposes, fused zero+cvt.
// ---------------------------------------------------------------------------

#define T_TOK 4096
#define DHID 768
#define NE_R 32
#define NE_S 8
#define F_S 2304
#define F_R 1536
#define MAXROWS 20480   // 160 tiles * 128
#define MAX_TILES 160

typedef float f32x4 __attribute__((ext_vector_type(4)));
typedef short s16x8 __attribute__((ext_vector_type(8)));

__device__ __forceinline__ short f2bf(float f) {
  union { float f; unsigned u; } v; v.f = f;
  unsigned r = v.u + 0x7fffu + ((v.u >> 16) & 1u);   // RNE
  return (short)(r >> 16);
}

// async global->LDS, 16B per lane, wave-uniform LDS base (per-lane global src OK)
#define GLD16(gsrc, ldst)                                                     \
  __builtin_amdgcn_global_load_lds(                                           \
      (const __attribute__((address_space(1))) void*)(gsrc),                  \
      (__attribute__((address_space(3))) void*)(ldst), 16, 0, 0)

// ---------------------------------------------------------------------------
// x fp32 -> bf16 (vectorized) + zero-init of routing scratch
__global__ __launch_bounds__(256) void cvt_x_kernel(const float* __restrict__ in,
    short* __restrict__ out, int* __restrict__ tlist, float* __restrict__ wslot,
    int* __restrict__ counts, int* __restrict__ cursor) {
  int i = blockIdx.x * 256 + threadIdx.x;
  if (i < T_TOK * DHID / 4) {
    float4 v = ((const float4*)in)[i];
    short4 o;
    o.x = f2bf(v.x); o.y = f2bf(v.y); o.z = f2bf(v.z); o.w = f2bf(v.w);
    ((short4*)out)[i] = o;
  }
  if (i < MAXROWS) { tlist[i] = 0; wslot[i] = 0.f; }
  if (i < 32) { counts[i] = 0; cursor[i] = 0; }
}

// ---------------------------------------------------------------------------
// Shared-expert weight transposes (swg, swu, swd). out[c*ldo+r] = in[r*C+c].
// MUST run before the shared GEMMs; does not touch the routed arena region
// that overlaps live shared buffers.
__global__ __launch_bounds__(256) void transpose_shared(
    const float* __restrict__ swg, const float* __restrict__ swu,
    const float* __restrict__ swd, short* __restrict__ wgT,
    short* __restrict__ wuT, short* __restrict__ wdT) {
  int bid = blockIdx.x;
  const float* in; short* out; int R, C, nbx; long ldo;
  if (bid < 13824)      { in = swg; out = wgT; R = DHID; C = F_S; ldo = DHID; nbx = 72; }
  else if (bid < 27648) { bid -= 13824; in = swu; out = wuT; R = DHID; C = F_S; ldo = DHID; nbx = 72; }
  else                  { bid -= 27648; in = swd; out = wdT; R = F_S; C = DHID; ldo = F_S; nbx = 24; }
  int per = nbx * (R / 32);
  int b = bid / per, rem = bid % per;
  int c0 = (rem % nbx) * 32, r0 = (rem / nbx) * 32;
  in  += (size_t)b * R * C;
  out += (size_t)b * R * C;
  int tx = threadIdx.x & 31, ty = threadIdx.x >> 5;  // 32 x 8
  __shared__ float tile[32][33];
#pragma unroll
  for (int i = 0; i < 32; i += 8)
    tile[ty + i][tx] = in[(size_t)(r0 + ty + i) * C + (c0 + tx)];
  __syncthreads();
#pragma unroll
  for (int i = 0; i < 32; i += 8)
    out[(size_t)(c0 + ty + i) * ldo + (r0 + tx)] = f2bf(tile[tx][ty + i]);
}

// Routed-expert weight transposes (rw1, rw2). MUST run only after the shared
// GEMMs complete (w1T/w2T overlap the then-dead wdT/Hsh regions).
__global__ __launch_bounds__(256) void transpose_routed(
    const float* __restrict__ rw1, const float* __restrict__ rw2,
    short* __restrict__ w1T, short* __restrict__ w2T) {
  int bid = blockIdx.x;
  const float* in; short* out; int R, C, nbx; long ldo;
  if (bid < 36864) { in = rw1; out = w1T; R = DHID; C = F_R; ldo = DHID; nbx = 48; }
  else             { bid -= 36864; in = rw2; out = w2T; R = F_R; C = DHID; ldo = F_R; nbx = 24; }
  int per = nbx * (R / 32);
  int b = bid / per, rem = bid % per;
  int c0 = (rem % nbx) * 32, r0 = (rem / nbx) * 32;
  in  += (size_t)b * R * C;
  out += (size_t)b * R * C;
  int tx = threadIdx.x & 31, ty = threadIdx.x >> 5;  // 32 x 8
  __shared__ float tile[32][33];
#pragma unroll
  for (int i = 0; i < 32; i += 8)
    tile[ty + i][tx] = in[(size_t)(r0 + ty + i) * C + (c0 + tx)];
  __syncthreads();
#pragma unroll
  for (int i = 0; i < 32; i += 8)
    out[(size_t)(c0 + ty + i) * ldo + (r0 + tx)] = f2bf(tile[tx][ty + i]);
}

// ---------------------------------------------------------------------------
// Router: fp32, one wave per token. sel[t][4], w4[t][4], counts, entropy.
__global__ __launch_bounds__(64) void router_kernel(const float* __restrict__ x,
    const float* __restrict__ rdown, const float* __restrict__ rup,
    int* __restrict__ sel, float* __restrict__ w4, int* __restrict__ counts,
    float* __restrict__ pent) {
  int t = blockIdx.x;
  int lane = threadIdx.x;
  __shared__ float xs[DHID];
  __shared__ float xrs[64];
  __shared__ float lg[32];
  const float* xt = x + (size_t)t * DHID;
  for (int i = lane; i < DHID; i += 64) xs[i] = xt[i];
  __syncthreads();
  float acc = 0.f;
#pragma unroll 8
  for (int d = 0; d < DHID; ++d) acc += xs[d] * rdown[d * 64 + lane];
  xrs[lane] = acc;
  __syncthreads();
  if (lane < 32) {
    float l = 0.f;
#pragma unroll 8
    for (int r = 0; r < 64; ++r) l += xrs[r] * rup[r * 32 + lane];
    lg[lane] = l;
  }
  __syncthreads();
  if (lane == 0) {
    int si[4]; float sv[4];
    unsigned taken = 0;
    for (int k = 0; k < 4; ++k) {            // top-4, ties -> lowest index
      float best = -3.4e38f; int bi = 0;
      for (int e = 0; e < 32; ++e)
        if (!((taken >> e) & 1u) && lg[e] > best) { best = lg[e]; bi = e; }
      taken |= 1u << bi; si[k] = bi; sv[k] = best;
    }
    float m = sv[0];
    float wv[4]; float zs = 0.f;
    for (int k = 0; k < 4; ++k) { wv[k] = __expf(sv[k] - m); zs += wv[k]; }
    for (int k = 0; k < 4; ++k) {
      sel[t * 4 + k] = si[k];
      w4[t * 4 + k] = wv[k] / zs;
      atomicAdd(&counts[si[k]], 1);
    }
    float Z = 0.f;
    for (int e = 0; e < 32; ++e) Z += __expf(lg[e] - m);
    float ent = 0.f;
    for (int e = 0; e < 32; ++e) {
      float p = __expf(lg[e] - m) / Z;
      ent -= p * logf(p + 1e-10f);
    }
    pent[t] = ent;
  }
}

// meta[e] = tile_base prefix (tiles of 128), meta[32] = total tiles
__global__ void meta_kernel(const int* __restrict__ counts, int* __restrict__ meta) {
  if (threadIdx.x == 0) {
    int acc = 0;
    for (int e = 0; e < 32; ++e) { meta[e] = acc; acc += (counts[e] + 127) >> 7; }
    meta[32] = acc;
  }
}

// slot assignment: value-deterministic (row placement doesn't change row math)
__global__ __launch_bounds__(256) void build_kernel(const int* __restrict__ sel,
    const float* __restrict__ w4, const int* __restrict__ meta, int* __restrict__ cursor,
    int* __restrict__ tlist, float* __restrict__ wslot, int* __restrict__ pos) {
  int t = blockIdx.x * 256 + threadIdx.x;
  if (t >= T_TOK) return;
#pragma unroll
  for (int k = 0; k < 4; ++k) {
    int e = sel[t * 4 + k];
    int slot = atomicAdd(&cursor[e], 1);
    int g = meta[e] * 128 + slot;
    tlist[g] = t; wslot[g] = w4[t * 4 + k]; pos[t * 4 + k] = g;
  }
}

// ---------------------------------------------------------------------------
// bf16 MFMA GEMM, BM=BN=128, BK=64, 4 waves, v_mfma_f32_16x16x32_bf16
// (PROVEN 0-conflict core from round 3; 32x32 variant regressed).
// LDS XOR-swizzle: phys chunk = logical ^ (row&7), staged via pre-swizzled
// global source (rule #21 involution), read back with the matching XOR.
// MODE 0: shared GEMM1 dual-B (gate,up), silu(g)*u -> bf16 Hsh  [+XCD swizzle]
// MODE 1: routed GEMM1 sparse gather, gelu*wslot -> bf16 Hr
// MODE 2: shared GEMM2, 2 experts/block accumulated, fp32 spart [+XCD swizzle]
// MODE 3: routed GEMM2 sparse, fp32 Y
template<int MODE>
__global__ __launch_bounds__(256, MODE == 0 ? 2 : 3) void gemm_k(
    const short* __restrict__ A, const short* __restrict__ B, const short* __restrict__ B2,
    short* __restrict__ outH, float* __restrict__ outF, const float* __restrict__ wslot,
    const int* __restrict__ meta, const int* __restrict__ tlist,
    int K, int lda, long zbstride, long ldo, long ocolz, long orowz, long acolz) {
  constexpr int BM = 128, BN = 128;
  constexpr int WM = 64, WN = 64, FM = 4, FN = 4;
  __shared__ short As[BM * 64];
  __shared__ short Bs[BN * 64];
  __shared__ short Bs2[(MODE == 0) ? BN * 64 : 64];

  int tid = threadIdx.x;
  int wv = tid >> 6, lane = tid & 63;
  int wr = wv >> 1, wc = wv & 1;
  int lrow = lane & 15, kg = lane >> 4;
  int lrow7 = lrow & 7;
  int z = blockIdx.z;

  int bx = blockIdx.x, by = blockIdx.y;
  if constexpr (MODE == 0 || MODE == 2) {
    // XCD-aware swizzle: give each XCD a contiguous N-slice (B-panel L2-hot).
    int gx = gridDim.x, gy = gridDim.y;
    int nwg = gx * gy;                   // 576 (MODE0) / 192 (MODE2), %8==0
    int orig = by * gx + bx;
    int swz = (orig & 7) * (nwg >> 3) + (orig >> 3);
    bx = swz / gy; by = swz % gy;
  }
  int n0 = bx * BN;

  int eidx = z;
  int g0 = 0, m0 = by * BM;
  if constexpr (MODE == 1 || MODE == 3) {
    int total = meta[32];
    int ty = blockIdx.y;
    if (ty >= total) return;
    int e = 0;
    while (meta[e + 1] <= ty) ++e;    // <=32 uniform iters
    eidx = e;
    g0 = ty * BM;
  }

  // staging geometry: round r covers rows r*32 + (tid>>3), 16B chunk (tid&7)
  int srow = tid >> 3;                             // 0..31
  int scol = ((tid & 7) ^ (srow & 7)) * 8;         // swizzled source chunk (shorts)

  f32x4 acc[FM][FN] = {};
  f32x4 acc2[(MODE == 0) ? FM : 1][(MODE == 0) ? FN : 1] = {};

  constexpr int EPB = (MODE == 2) ? 2 : 1;         // experts per block
#pragma unroll 1
  for (int ei = 0; ei < EPB; ++ei) {
    int e = (MODE == 2) ? (z * 2 + ei) : eidx;
    const short* Bb = B + (size_t)e * zbstride + (size_t)n0 * K;
    const short* B2b = (MODE == 0) ? (B2 + (size_t)e * zbstride + (size_t)n0 * K) : B;

    const short *as0, *as1, *as2, *as3;
    {
      auto arow = [&](int row) -> const short* {
        if constexpr (MODE == 1) {
          return A + (size_t)tlist[g0 + row] * lda + scol;
        } else if constexpr (MODE == 2) {
          return A + ((size_t)(m0 + row)) * lda + (size_t)e * acolz + scol;
        } else if constexpr (MODE == 3) {
          return A + ((size_t)(g0 + row)) * lda + scol;
        } else {
          return A + ((size_t)(m0 + row)) * lda + scol;
        }
      };
      as0 = arow(srow); as1 = arow(32 + srow); as2 = arow(64 + srow); as3 = arow(96 + srow);
    }
    const short* bs0 = Bb + (size_t)srow * K + scol;
    const short* bs1 = bs0 + (size_t)32 * K;
    const short* bs2 = bs0 + (size_t)64 * K;
    const short* bs3 = bs0 + (size_t)96 * K;
    const short* c2s0 = B2b + (size_t)srow * K + scol;
    const short* c2s1 = c2s0 + (size_t)32 * K;
    const short* c2s2 = c2s0 + (size_t)64 * K;
    const short* c2s3 = c2s0 + (size_t)96 * K;

    for (int kt = 0; kt < K; kt += 64) {
      GLD16(as0 + kt, As + (0 * 32 + wv * 8) * 64);
      GLD16(as1 + kt, As + (1 * 32 + wv * 8) * 64);
      GLD16(as2 + kt, As + (2 * 32 + wv * 8) * 64);
      GLD16(as3 + kt, As + (3 * 32 + wv * 8) * 64);
      GLD16(bs0 + kt, Bs + (0 * 32 + wv * 8) * 64);
      GLD16(bs1 + kt, Bs + (1 * 32 + wv * 8) * 64);
      GLD16(bs2 + kt, Bs + (2 * 32 + wv * 8) * 64);
      GLD16(bs3 + kt, Bs + (3 * 32 + wv * 8) * 64);
      if constexpr (MODE == 0) {
        GLD16(c2s0 + kt, Bs2 + (0 * 32 + wv * 8) * 64);
        GLD16(c2s1 + kt, Bs2 + (1 * 32 + wv * 8) * 64);
        GLD16(c2s2 + kt, Bs2 + (2 * 32 + wv * 8) * 64);
        GLD16(c2s3 + kt, Bs2 + (3 * 32 + wv * 8) * 64);
      }
      __syncthreads();
#pragma unroll
      for (int ks = 0; ks < 2; ++ks) {
        int pc = ((ks * 4 + kg) ^ lrow7) * 8;        // swizzled chunk (shorts)
        s16x8 af[FM], bb[FN];
#pragma unroll
        for (int i = 0; i < FM; ++i)
          af[i] = *(const s16x8*)&As[(wr * WM + i * 16 + lrow) * 64 + pc];
#pragma unroll
        for (int j = 0; j < FN; ++j)
          bb[j] = *(const s16x8*)&Bs[(wc * WN + j * 16 + lrow) * 64 + pc];
#pragma unroll
        for (int i = 0; i < FM; ++i)
#pragma unroll
          for (int j = 0; j < FN; ++j)
            acc[i][j] = __builtin_amdgcn_mfma_f32_16x16x32_bf16(af[i], bb[j], acc[i][j], 0, 0, 0);
        if constexpr (MODE == 0) {
          s16x8 b2[FN];
#pragma unroll
          for (int j = 0; j < FN; ++j)
            b2[j] = *(const s16x8*)&Bs2[(wc * WN + j * 16 + lrow) * 64 + pc];
#pragma unroll
          for (int i = 0; i < FM; ++i)
#pragma unroll
            for (int j = 0; j < FN; ++j)
              acc2[i][j] = __builtin_amdgcn_mfma_f32_16x16x32_bf16(af[i], b2[j], acc2[i][j], 0, 0, 0);
        }
      }
      __syncthreads();
    }
  }

  // epilogue: C/D layout col=lane&15, row=(lane>>4)*4+r  [verified m89]
#pragma unroll
  for (int i = 0; i < FM; ++i) {
#pragma unroll
    for (int r = 0; r < 4; ++r) {
      int rl = wr * WM + i * 16 + kg * 4 + r;
      float wsc = 0.f;
      if constexpr (MODE == 1) wsc = wslot[g0 + rl];
#pragma unroll
      for (int j = 0; j < FN; ++j) {
        int col = n0 + wc * WN + j * 16 + lrow;
        float v = acc[i][j][r];
        if constexpr (MODE == 0) {
          float u = acc2[i][j][r];
          float h = v / (1.f + __expf(-v)) * u;                       // silu(g)*u
          outH[(size_t)(m0 + rl) * ldo + (size_t)z * ocolz + col] = f2bf(h);
        } else if constexpr (MODE == 1) {
          float h = 0.5f * v * (1.f + erff(v * 0.70710678118f)) * wsc; // gelu * gate
          outH[(size_t)(g0 + rl) * ldo + col] = f2bf(h);
        } else if constexpr (MODE == 2) {
          outF[(size_t)z * orowz + (size_t)(m0 + rl) * DHID + col] = v;
        } else {
          outF[(size_t)(g0 + rl) * DHID + col] = v;
        }
      }
    }
  }
}

// ---------------------------------------------------------------------------
// combine: out = mean(4 partials, each = 2 experts) + gather-sum of Y rows
__global__ __launch_bounds__(256) void combine_kernel(const float* __restrict__ spart,
    const float* __restrict__ Y, const int* __restrict__ pos,
    float* __restrict__ out, float* __restrict__ pnorm) {
  int t = blockIdx.x, tid = threadIdx.x;
  int p0 = pos[t * 4], p1 = pos[t * 4 + 1], p2 = pos[t * 4 + 2], p3 = pos[t * 4 + 3];
  size_t base = (size_t)t * DHID;
  float s2 = 0.f, r2 = 0.f;
  for (int d = tid; d < DHID; d += 256) {
    float s = 0.f;
#pragma unroll
    for (int e = 0; e < 4; ++e) s += spart[(size_t)e * T_TOK * DHID + base + d];
    s *= 0.125f;
    float r = Y[(size_t)p0 * DHID + d] + Y[(size_t)p1 * DHID + d] +
              Y[(size_t)p2 * DHID + d] + Y[(size_t)p3 * DHID + d];
    out[base + d] = s + r;
    s2 += s * s; r2 += r * r;
  }
  for (int o = 32; o > 0; o >>= 1) { s2 += __shfl_down(s2, o); r2 += __shfl_down(r2, o); }
  __shared__ float red[8];
  int wv = tid >> 6, lane = tid & 63;
  if (lane == 0) { red[wv] = s2; red[4 + wv] = r2; }
  __syncthreads();
  if (tid == 0) {
    float st = red[0] + red[1] + red[2] + red[3];
    float rt = red[4] + red[5] + red[6] + red[7];
    pnorm[t] = sqrtf(st);
    pnorm[T_TOK + t] = sqrtf(rt);
  }
}

__global__ __launch_bounds__(256) void finalize_kernel(const int* __restrict__ counts,
    const float* __restrict__ pent, const float* __restrict__ pnorm, float* __restrict__ o) {
  int tid = threadIdx.x;
  float es = 0.f, ss = 0.f, rs = 0.f;
  for (int i = tid; i < T_TOK; i += 256) {
    es += pent[i]; ss += pnorm[i]; rs += pnorm[T_TOK + i];
  }
  float vs = 0.f;
  if (tid < 32) { float d = (float)counts[tid] - 512.f; vs = d * d; }
  for (int off = 32; off > 0; off >>= 1) {
    es += __shfl_down(es, off); ss += __shfl_down(ss, off);
    rs += __shfl_down(rs, off); vs += __shfl_down(vs, off);
  }
  __shared__ float red[16];
  int wv = tid >> 6, lane = tid & 63;
  if (lane == 0) { red[wv] = es; red[4 + wv] = ss; red[8 + wv] = rs; red[12 + wv] = vs; }
  __syncthreads();
  if (tid == 0) {
    es = red[0] + red[1] + red[2] + red[3];
    ss = red[4] + red[5] + red[6] + red[7];
    rs = red[8] + red[9] + red[10] + red[11];
    vs = red[12] + red[13] + red[14] + red[15];
    o[0] = vs / 31.f;                     // load_balance_loss (ddof=1, mean=512 exact)
    o[1] = es / (float)T_TOK;             // router_entropy
    o[2] = fabsf(ss - rs) / (float)T_TOK; // balance_loss
  }
}

// ---------------------------------------------------------------------------
extern "C" void kernel_launch(void* const* d_in, const int* in_sizes, int n_in,
                              void* d_out, int out_size, void* d_ws, size_t ws_size,
                              hipStream_t stream) {
  const float* x   = (const float*)d_in[0];
  const float* swg = (const float*)d_in[1];
  const float* swu = (const float*)d_in[2];
  const float* swd = (const float*)d_in[3];
  const float* rw1 = (const float*)d_in[4];
  const float* rw2 = (const float*)d_in[5];
  const float* rdn = (const float*)d_in[6];
  const float* rup = (const float*)d_in[7];
  float* fout = (float*)d_out;

  // ---- workspace layout ----
  char* w = (char*)d_ws;
  size_t off = 0;
  auto take = [&](size_t bytes) { char* p = w + off; off = (off + bytes + 255) & ~(size_t)255; return p; };
  short* xbf   = (short*)take((size_t)T_TOK * DHID * 2);
  int*   sel   = (int*)  take((size_t)T_TOK * 4 * 4);
  float* w4    = (float*)take((size_t)T_TOK * 4 * 4);
  int*   pos   = (int*)  take((size_t)T_TOK * 4 * 4);
  int*   counts= (int*)  take(32 * 4);
  int*   cursor= (int*)  take(32 * 4);
  int*   meta  = (int*)  take(64 * 4);
  int*   tlist = (int*)  take((size_t)MAXROWS * 4);
  float* wslot = (float*)take((size_t)MAXROWS * 4);
  float* pent  = (float*)take((size_t)T_TOK * 4);
  float* pnorm = (float*)take((size_t)2 * T_TOK * 4);
  float* spart = (float*)take((size_t)4 * T_TOK * DHID * 4);   // 50.3 MB
  char*  arena = w + off;

  // arena (phase-overlapped; LIFETIME ORDER MATTERS):
  // shared phase:  [wgT 28.3][wuT 28.3][wdT 28.3][Hsh 151]  = 236 MB
  // routed phase:  [Y 62.9][w1T 75.5][w2T 75.5][Hr 62.9]    = 277 MB
  // transpose_routed (w1T,w2T) must run AFTER the shared GEMMs (overlap wdT/Hsh).
  short* wgT = (short*)arena;
  short* wuT = wgT + (size_t)NE_S * F_S * DHID;
  short* wdT = wuT + (size_t)NE_S * F_S * DHID;
  short* Hsh = wdT + (size_t)NE_S * F_S * DHID;
  float* Y   = (float*)arena;
  short* w1T = (short*)(arena + (size_t)MAXROWS * DHID * 4);
  short* w2T = w1T + (size_t)NE_R * F_R * DHID;
  short* Hr  = w2T + (size_t)NE_R * F_R * DHID;

  // ---- setup / router ----
  cvt_x_kernel<<<(T_TOK * DHID / 4 + 255) / 256, 256, 0, stream>>>(x, xbf, tlist, wslot, counts, cursor);
  router_kernel<<<T_TOK, 64, 0, stream>>>(x, rdn, rup, sel, w4, counts, pent);
  meta_kernel<<<1, 64, 0, stream>>>(counts, meta);
  build_kernel<<<T_TOK / 256, 256, 0, stream>>>(sel, w4, meta, cursor, tlist, wslot, pos);

  // ---- shared experts ----
  transpose_shared<<<41472, 256, 0, stream>>>(swg, swu, swd, wgT, wuT, wdT);
  gemm_k<0><<<dim3(F_S / 128, T_TOK / 128, NE_S), 256, 0, stream>>>(
      xbf, wgT, wuT, Hsh, nullptr, nullptr, nullptr, nullptr,
      DHID, DHID, (long)F_S * DHID, (long)NE_S * F_S, (long)F_S, 0, 0);
  gemm_k<2><<<dim3(DHID / 128, T_TOK / 128, NE_S / 2), 256, 0, stream>>>(
      Hsh, wdT, nullptr, nullptr, spart, nullptr, nullptr, nullptr,
      F_S, NE_S * F_S, (long)DHID * F_S, DHID, 0, (long)T_TOK * DHID, (long)F_S);

  // ---- routed experts (sparse, tile-compacted) ----
  transpose_routed<<<73728, 256, 0, stream>>>(rw1, rw2, w1T, w2T);
  gemm_k<1><<<dim3(F_R / 128, MAX_TILES, 1), 256, 0, stream>>>(
      xbf, w1T, nullptr, Hr, nullptr, wslot, meta, tlist,
      DHID, DHID, (long)F_R * DHID, (long)F_R, 0, 0, 0);
  gemm_k<3><<<dim3(DHID / 128, MAX_TILES, 1), 256, 0, stream>>>(
      Hr, w2T, nullptr, nullptr, Y, nullptr, meta, tlist,
      F_R, F_R, (long)DHID * F_R, DHID, 0, 0, 0);

  // ---- combine + scalars ----
  combine_kernel<<<T_TOK, 256, 0, stream>>>(spart, Y, pos, fout, pnorm);
  finalize_kernel<<<1, 256, 0, stream>>>(counts, pent, pnorm, fout + (size_t)T_TOK * DHID);
}